// Round 9
// baseline (1095.598 us; speedup 1.0000x reference)
//
#include <hip/hip_runtime.h>

#define VOX (128*128*32)   // 524288 voxels
#define CCH 64
#define NCL 20
#define DD 128
#define HH 128
#define WW 32
#define ZT 8
#define EPSV 1e-5f
#define THRESV 0.2f

// ---- order-preserving float <-> uint key for atomic min/max ----
__device__ __forceinline__ unsigned keyOf(float f){
    unsigned u = __float_as_uint(f);
    return (u & 0x80000000u) ? ~u : (u | 0x80000000u);
}
__device__ __forceinline__ float keyInv(unsigned k){
    unsigned u = (k & 0x80000000u) ? (k & 0x7fffffffu) : ~k;
    return __uint_as_float(u);
}

__global__ void k_init(unsigned* keys, float* zpg){
    int i = threadIdx.x;
    if (i < NCL){ keys[i] = 0xFFFFFFFFu; keys[NCL+i] = 0u; }
    #pragma unroll
    for (int k = 0; k < 4; ++k) zpg[k*64 + i] = 0.f;
}

// ---- Pass A: logit (einsum + bias), softmax masks, per-voxel mean/max over C ----
__global__ __launch_bounds__(256) void k_logit_softmax(
    const float* __restrict__ x, const float* __restrict__ clsw,
    const float* __restrict__ clsb, float* __restrict__ masks,
    float* __restrict__ logit, float* __restrict__ mx, float* __restrict__ Mx)
{
    __shared__ float sw[NCL*CCH];
    __shared__ float sb[NCL];
    int tid = threadIdx.x;
    for (int q = tid; q < NCL*CCH; q += 256) sw[q] = clsw[q];
    if (tid < NCL) sb[tid] = clsb[tid];
    __syncthreads();
    int v = blockIdx.x*256 + tid;
    float acc[NCL];
    #pragma unroll
    for (int o=0;o<NCL;o++) acc[o] = sb[o];
    float s = 0.f, mm = -1e30f;
    for (int c=0;c<CCH;c++){
        float xv = x[c*VOX + v];
        s += xv; mm = fmaxf(mm, xv);
        #pragma unroll
        for (int o=0;o<NCL;o++) acc[o] = fmaf(xv, sw[o*CCH + c], acc[o]);
    }
    mx[v] = s * (1.f/64.f);
    Mx[v] = mm;
    float lm = acc[0];
    #pragma unroll
    for (int o=1;o<NCL;o++) lm = fmaxf(lm, acc[o]);
    float es = 0.f;
    #pragma unroll
    for (int o=0;o<NCL;o++){
        logit[o*VOX + v] = acc[o];
        float e = expf(acc[o] - lm);
        es += e; acc[o] = e;
    }
    float inv = 1.f/es;
    #pragma unroll
    for (int o=0;o<NCL;o++) masks[o*VOX + v] = acc[o]*inv;
}

// ---- Pass B: z-marching FIR conv, async double-buffered LDS, exact counted vmcnt ----
// block = 128 thr (2 waves): y = tid>>3 (16 rows), x0 = (tid&7)*4 (4 outputs).
// grid = (20 cls, 16 z, 8 y) = 2560 blocks; LDS 18.4KB -> 8 blocks/CU = 16 waves/CU
// (4 waves/SIMD -- the latency-hiding residency rounds 3-8 never had).
// Slice = 3 raw planes (mask,mx,Mx) of [22 rows x 32], plain row-major (conflict-free).
// 9 global_load_lds(16B)/slice: wave0 issues 5, wave1 4 -> exact vmcnt(L or L+1).
// OOB lanes read a zero page (full EXEC -> counts provable). Store AFTER issue_slice.

#define F4(A, WV, q0,q1,q2,q3) { A.x=fmaf(q0,WV,A.x); A.y=fmaf(q1,WV,A.y); \
                                 A.z=fmaf(q2,WV,A.z); A.w=fmaf(q3,WV,A.w); }
#define DZ4(A, WP, P) { \
    F4(A,(WP)[0], P##0,P##1,P##2,P##3) \
    F4(A,(WP)[1], P##1,P##2,P##3,P##4) \
    F4(A,(WP)[2], P##2,P##3,P##4,P##5) \
    F4(A,(WP)[3], P##3,P##4,P##5,P##6) \
    F4(A,(WP)[4], P##4,P##5,P##6,P##7) \
    F4(A,(WP)[5], P##5,P##6,P##7,P##8) \
    F4(A,(WP)[6], P##6,P##7,P##8,P##9) }

#define TGROUP4(P, WT) { \
    const float* wd_ = (WT) + dy*7; \
    if (ok6) DZ4(a6, wd_+0,   P) \
    if (ok5) DZ4(a5, wd_+49,  P) \
    if (ok4) DZ4(a4, wd_+98,  P) \
    if (ok3) DZ4(a3, wd_+147, P) \
    if (ok2) DZ4(a2, wd_+196, P) \
    if (ok1) DZ4(a1, wd_+245, P) \
    if (ok0) DZ4(a0, wd_+294, P) }

#define PLANE_F 704      // 22 rows x 32 floats, plain row-major
#define SLICE_Q 528      // real granules (3 planes x 176)
#define BUF_F   2304     // padded slice floats (9 issues x 256)
#define LDS_F   4608     // 2 buffers

__device__ __forceinline__ void issue_slice(const float* mk, const float* mxp, const float* Mxp,
        const float* zpg, float* FLf, int bufF, int zi, int y0, int lane, int wid)
{
    const bool zok = (unsigned)zi < (unsigned)DD;
    const float* srcs[3] = { mk, mxp, Mxp };
    #pragma unroll
    for (int i = 0; i < 9; ++i){
        if ((i < 5) != (wid == 0)) continue;     // wave0: 5 issues, wave1: 4
        int q = i*64 + lane;
        const float* g;
        if (q < SLICE_Q && zok){
            int f   = q / 176;
            int r   = q - f*176;
            int row = r >> 3, xq = r & 7;        // plain slot (no swizzle)
            int gy  = y0 - 3 + row;
            if ((unsigned)gy < (unsigned)HH)
                g = srcs[f] + (((size_t)(zi*HH + gy)*8 + xq) << 2);
            else
                g = zpg + lane*4;
        } else {
            g = zpg + lane*4;
        }
        float* l = FLf + bufF + i*256;           // wave-uniform; HW adds lane*16B
        __builtin_amdgcn_global_load_lds(
            (const __attribute__((address_space(1))) void*)g,
            (__attribute__((address_space(3))) void*)l, 16, 0, 0);
    }
}

__global__ __launch_bounds__(128, 4) void k_conv9(const float* __restrict__ masksAll,
        const float* __restrict__ mxp, const float* __restrict__ Mxp,
        const float* __restrict__ cfr, float* __restrict__ G,
        const float* __restrict__ zpg)
{
    __shared__ __align__(16) float FLf[LDS_F];
    const int cls = blockIdx.x;
    const int z0  = blockIdx.y * ZT;
    const int y0  = blockIdx.z * 16;
    const int tid = threadIdx.x;
    const int lane = tid & 63, wid = tid >> 6;
    const int y  = tid >> 3;          // 0..15
    const int xg = tid & 7;           // 0..7
    const int x0 = xg * 4;
    const bool lo_inv = (xg == 0), hi_inv = (xg == 7);
    const float* mk   = masksAll + (size_t)cls * VOX;
    const float* wcls = cfr + cls*1029;          // uniform -> scalar loads
    float* Gc = G + (size_t)cls * VOX;

    issue_slice(mk, mxp, Mxp, zpg, FLf, 0,     z0-3, y0, lane, wid);
    issue_slice(mk, mxp, Mxp, zpg, FLf, BUF_F, z0-2, y0, lane, wid);

    float4 a0{},a1{},a2{},a3{},a4{},a5{},a6{};
    int cur = 0;

    #pragma unroll 1
    for (int zi = z0 - 3; zi <= z0 + ZT + 2; ++zi){
        // exact wait: leave next slice's loads (+1 store if last phase stored) in flight
        const bool pst = (zi >= z0 + 4);
        if (wid == 0){ if (pst) asm volatile("s_waitcnt vmcnt(6)" ::: "memory");
                       else     asm volatile("s_waitcnt vmcnt(5)" ::: "memory"); }
        else         { if (pst) asm volatile("s_waitcnt vmcnt(5)" ::: "memory");
                       else     asm volatile("s_waitcnt vmcnt(4)" ::: "memory"); }
        __builtin_amdgcn_sched_barrier(0);
        __builtin_amdgcn_s_barrier();
        __builtin_amdgcn_sched_barrier(0);

        const int lo = z0 + 3 - zi;                // okJ: J>=lo && J-lo<ZT (wave-uniform)
        const bool ok0 = (0>=lo) && (0-lo<ZT);
        const bool ok1 = (1>=lo) && (1-lo<ZT);
        const bool ok2 = (2>=lo) && (2-lo<ZT);
        const bool ok3 = (3>=lo) && (3-lo<ZT);
        const bool ok4 = (4>=lo) && (4-lo<ZT);
        const bool ok5 = (5>=lo) && (5-lo<ZT);
        const bool ok6 = (6>=lo) && (6-lo<ZT);

        #pragma unroll 1
        for (int dy = 0; dy < 7; ++dy){
            const int r   = y + dy;
            const float* Pm = FLf + cur*BUF_F + r*32;
            const float* Pa = Pm + PLANE_F;
            const float* Pb = Pa + PLANE_F;
            const int c0 = (xg > 0 ? xg-1 : 0)*4;
            const int c1 = xg*4;
            const int c2 = (xg < 7 ? xg+1 : 7)*4;
            const float4 M0 = *(const float4*)(Pm + c0);
            const float4 M1 = *(const float4*)(Pm + c1);
            const float4 M2 = *(const float4*)(Pm + c2);
            const float pm0 = lo_inv ? 0.f : M0.y;
            const float pm1 = lo_inv ? 0.f : M0.z;
            const float pm2 = lo_inv ? 0.f : M0.w;
            const float pm3 = M1.x, pm4 = M1.y, pm5 = M1.z, pm6 = M1.w;
            const float pm7 = hi_inv ? 0.f : M2.x;
            const float pm8 = hi_inv ? 0.f : M2.y;
            const float pm9 = hi_inv ? 0.f : M2.z;

            {   // t = 0: field mask*mx
                const float4 A0 = *(const float4*)(Pa + c0);
                const float4 A1 = *(const float4*)(Pa + c1);
                const float4 A2 = *(const float4*)(Pa + c2);
                const float pa0 = pm0*A0.y, pa1 = pm1*A0.z, pa2 = pm2*A0.w;
                const float pa3 = pm3*A1.x, pa4 = pm4*A1.y, pa5 = pm5*A1.z, pa6 = pm6*A1.w;
                const float pa7 = pm7*A2.x, pa8 = pm8*A2.y, pa9 = pm9*A2.z;
                TGROUP4(pa, wcls)
            }
            {   // t = 1: field mask*Mx
                const float4 B0 = *(const float4*)(Pb + c0);
                const float4 B1 = *(const float4*)(Pb + c1);
                const float4 B2 = *(const float4*)(Pb + c2);
                const float pb0 = pm0*B0.y, pb1 = pm1*B0.z, pb2 = pm2*B0.w;
                const float pb3 = pm3*B1.x, pb4 = pm4*B1.y, pb5 = pm5*B1.z, pb6 = pm6*B1.w;
                const float pb7 = pm7*B2.x, pb8 = pm8*B2.y, pb9 = pm9*B2.z;
                TGROUP4(pb, wcls + 343)
            }
            // t = 2: field mask
            TGROUP4(pm, wcls + 686)
        }

        __builtin_amdgcn_sched_barrier(0);
        __builtin_amdgcn_s_barrier();            // all waves done reading buf[cur]
        __builtin_amdgcn_sched_barrier(0);
        issue_slice(mk, mxp, Mxp, zpg, FLf, cur*BUF_F, zi+2, y0, lane, wid);

        if (zi >= z0 + 3){                       // store AFTER loads (vmcnt order: [loads, store])
            const int oidx = ((zi-3)*HH + (y0 + y))*WW + x0;
            *(float4*)(Gc + oidx) = a0;
        }
        a0=a1; a1=a2; a2=a3; a3=a4; a4=a5; a5=a6;
        a6 = make_float4(0.f,0.f,0.f,0.f);
        cur ^= 1;
    }
    asm volatile("s_waitcnt vmcnt(0)" ::: "memory");  // drain dummy DMA before LDS dealloc
}

// ---- sigmoid + heat min/max + ma write (BW-bound finalize of conv) ----
__global__ __launch_bounds__(256) void k_heat(const float* __restrict__ masks,
        const float* __restrict__ mx, float* G, unsigned* __restrict__ keys)
{
    __shared__ float r4[8];
    const int i = blockIdx.y;
    const int tid = threadIdx.x;
    const size_t v4 = (size_t)blockIdx.x*256 + tid;
    float4 acc = ((const float4*)(G + (size_t)i*VOX))[v4];
    float4 m4  = ((const float4*)(masks + (size_t)i*VOX))[v4];
    float4 x4  = ((const float4*)mx)[v4];
    float4 ma;
    ma.x = m4.x/(1.f + expf(-acc.x));
    ma.y = m4.y/(1.f + expf(-acc.y));
    ma.z = m4.z/(1.f + expf(-acc.z));
    ma.w = m4.w/(1.f + expf(-acc.w));
    ((float4*)(G + (size_t)i*VOX))[v4] = ma;
    float h0 = ma.x*x4.x, h1 = ma.y*x4.y, h2 = ma.z*x4.z, h3 = ma.w*x4.w;
    float hmn = fminf(fminf(h0,h1), fminf(h2,h3));
    float hmx = fmaxf(fmaxf(h0,h1), fmaxf(h2,h3));
    #pragma unroll
    for (int off = 32; off > 0; off >>= 1){
        hmn = fminf(hmn, __shfl_xor(hmn, off));
        hmx = fmaxf(hmx, __shfl_xor(hmx, off));
    }
    if ((tid & 63) == 0){ r4[(tid>>6)*2] = hmn; r4[(tid>>6)*2+1] = hmx; }
    __syncthreads();
    if (tid == 0){
        float a = fminf(fminf(r4[0],r4[2]), fminf(r4[4],r4[6]));
        float b = fmaxf(fmaxf(r4[1],r4[3]), fmaxf(r4[5],r4[7]));
        atomicMin(&keys[i],     keyOf(a));
        atomicMax(&keys[NCL+i], keyOf(b));
    }
}

__global__ void k_thr(const unsigned* __restrict__ keys, float* __restrict__ hminA,
                      float* __restrict__ invR){
    int i = threadIdx.x;
    if (i < NCL){
        float hm = keyInv(keys[i]);
        float hM = keyInv(keys[NCL+i]);
        hminA[i] = hm;
        invR[i] = 1.f/(hM - hm);
    }
}

// ---- g = ma * (norm > 0.2), in place ----
__global__ __launch_bounds__(256) void k_region(float* G, const float* __restrict__ mx,
        const float* __restrict__ hminA, const float* __restrict__ invR)
{
    int i = blockIdx.y;
    int v = blockIdx.x*256 + threadIdx.x;
    float ma = G[i*VOX + v];
    float heat = ma * mx[v];
    float norm = (heat - hminA[i]) * invR[i];
    G[i*VOX + v] = (norm > THRESV) ? ma : 0.f;
}

// ---- per-(class,channel) sums S1 = sum x*g, S2 = sum (x*g)^2 ----
// grid 512 (2 blocks/CU, 8 waves/CU) -- round-8's 256 was 1 wave/SIMD, zero latency hiding.
__global__ __launch_bounds__(256) void k_stats(const float* __restrict__ x,
        const float* G, float* __restrict__ part)
{
    int tid = threadIdx.x;
    int c = tid & 63, vg = tid >> 6;
    int v0 = blockIdx.x * 1024;
    float s1[NCL], s2[NCL];
    #pragma unroll
    for (int i=0;i<NCL;i++){ s1[i]=0.f; s2[i]=0.f; }
    const float* xc = x + c*VOX;
    for (int k=0;k<256;k++){
        int v = v0 + (k<<2) + vg;
        float xv = xc[v];
        #pragma unroll
        for (int i=0;i<NCL;i++){
            float p = xv * G[i*VOX + v];
            s1[i] += p;
            s2[i] = fmaf(p, p, s2[i]);
        }
    }
    __shared__ float red[4][64][2*NCL];
    #pragma unroll
    for (int i=0;i<NCL;i++){ red[vg][c][i] = s1[i]; red[vg][c][NCL+i] = s2[i]; }
    __syncthreads();
    if (vg == 0){
        float* dst = part + (size_t)blockIdx.x * (NCL*CCH*2);
        for (int i=0;i<NCL;i++){
            float a = red[0][c][i]+red[1][c][i]+red[2][c][i]+red[3][c][i];
            float b = red[0][c][NCL+i]+red[1][c][NCL+i]+red[2][c][NCL+i]+red[3][c][NCL+i];
            dst[i*CCH*2 + c*2 + 0] = a;
            dst[i*CCH*2 + c*2 + 1] = b;
        }
    }
}

// ---- finish stats: a = gamma*rinv, kc = beta - m*rinv*gamma (512 partials, 4-way split) ----
__global__ __launch_bounds__(256) void k_params(const float* __restrict__ part,
        const float* __restrict__ gamma, const float* __restrict__ beta,
        float* __restrict__ aArr, float* __restrict__ kcArr)
{
    int i = blockIdx.x;
    int c = threadIdx.x & 63, q = threadIdx.x >> 6;
    float s1 = 0.f, s2 = 0.f;
    for (int b = q; b < 512; b += 4){
        const float* p = part + (size_t)b*(NCL*CCH*2) + i*CCH*2 + c*2;
        s1 += p[0]; s2 += p[1];
    }
    __shared__ float red[4][64][2];
    red[q][c][0] = s1; red[q][c][1] = s2;
    __syncthreads();
    if (q == 0){
        s1 = red[0][c][0]+red[1][c][0]+red[2][c][0]+red[3][c][0];
        s2 = red[0][c][1]+red[1][c][1]+red[2][c][1]+red[3][c][1];
        float m   = s1 * (1.f/(float)VOX);
        float var = s2 * (1.f/(float)VOX) - m*m;
        float rinv = 1.f/sqrtf(var + EPSV);
        float gm = gamma[c];
        aArr[i*CCH + c]  = gm*rinv;
        kcArr[i*CCH + c] = beta[c] - m*rinv*gm;
    }
}

__global__ void k_kcol(const float* __restrict__ kcArr, float* __restrict__ KcA){
    int c = threadIdx.x;
    if (c < CCH){
        float s = 0.f;
        for (int i=0;i<NCL;i++) s += kcArr[i*CCH + c];
        KcA[c] = s;
    }
}

// ---- final: out[c,v] = relu( x*Sum_i g_i*a_ic + K[c] ), in-place over d_out ----
__global__ __launch_bounds__(256) void k_final(const float* __restrict__ x,
        float* outAll, const float* __restrict__ aArr, const float* __restrict__ KcA)
{
    __shared__ float aL[NCL*CCH];
    __shared__ float KL[CCH];
    int tid = threadIdx.x;
    for (int q=tid; q<NCL*CCH; q+=256) aL[q] = aArr[q];
    if (tid < CCH) KL[tid] = KcA[tid];
    __syncthreads();
    int v = blockIdx.x*256 + tid;
    const float* Gp = outAll + (size_t)NCL*VOX;
    float g[NCL];
    #pragma unroll
    for (int i=0;i<NCL;i++) g[i] = Gp[i*VOX + v];
    #pragma unroll 4
    for (int c=0;c<CCH;c++){
        float P = 0.f;
        #pragma unroll
        for (int i=0;i<NCL;i++) P = fmaf(g[i], aL[i*CCH + c], P);
        float xv = x[c*VOX + v];
        outAll[c*VOX + v] = fmaxf(0.f, fmaf(xv, P, KL[c]));
    }
}

extern "C" void kernel_launch(void* const* d_in, const int* in_sizes, int n_in,
                              void* d_out, int out_size, void* d_ws, size_t ws_size,
                              hipStream_t stream)
{
    const float* x     = (const float*)d_in[0];
    const float* clsw  = (const float*)d_in[1];
    const float* clsb  = (const float*)d_in[2];
    const float* cfr   = (const float*)d_in[3];
    const float* gamma = (const float*)d_in[4];
    const float* beta  = (const float*)d_in[5];

    float* out   = (float*)d_out;
    float* logit = out + (size_t)CCH*VOX;     // second output
    float* masks = out;                       // scratch: out[0 .. 20V)
    float* G     = out + (size_t)NCL*VOX;     // scratch: out[20V .. 40V)

    float* ws    = (float*)d_ws;
    float* mxp   = ws;                        // V
    float* Mxp   = ws + VOX;                  // V
    unsigned* keys = (unsigned*)(ws + 2*(size_t)VOX);   // 40
    float* hminA = ws + 2*(size_t)VOX + 64;   // 20
    float* invR  = hminA + NCL;               // 20
    float* part  = ws + 2*(size_t)VOX + 128;  // 512*2560
    float* aArr  = part + 512*(NCL*CCH*2);    // 1280
    float* kcArr = aArr + NCL*CCH;            // 1280
    float* KcA   = kcArr + NCL*CCH;           // 64
    float* zpg   = KcA + CCH;                 // 256 (zero page for OOB lanes)

    k_init<<<1, 64, 0, stream>>>(keys, zpg);
    k_logit_softmax<<<VOX/256, 256, 0, stream>>>(x, clsw, clsb, masks, logit, mxp, Mxp);
    k_conv9<<<dim3(NCL, 16, 8), 128, 0, stream>>>(masks, mxp, Mxp, cfr, G, zpg);
    k_heat<<<dim3(VOX/1024, NCL), 256, 0, stream>>>(masks, mxp, G, keys);
    k_thr<<<1, 32, 0, stream>>>(keys, hminA, invR);
    k_region<<<dim3(VOX/256, NCL), 256, 0, stream>>>(G, mxp, hminA, invR);
    k_stats<<<512, 256, 0, stream>>>(x, G, part);
    k_params<<<NCL, 256, 0, stream>>>(part, gamma, beta, aArr, kcArr);
    k_kcol<<<1, CCH, 0, stream>>>(kcArr, KcA);
    k_final<<<VOX/256, 256, 0, stream>>>(x, out, aArr, KcA);
}

// Round 10
// 765.791 us; speedup vs baseline: 1.4307x; 1.4307x over previous
//
#include <hip/hip_runtime.h>

#define VOX (128*128*32)   // 524288 voxels
#define CCH 64
#define NCL 20
#define DD 128
#define HH 128
#define WW 32
#define ZT 8
#define EPSV 1e-5f
#define THRESV 0.2f

// ---- order-preserving float <-> uint key for atomic min/max ----
__device__ __forceinline__ unsigned keyOf(float f){
    unsigned u = __float_as_uint(f);
    return (u & 0x80000000u) ? ~u : (u | 0x80000000u);
}
__device__ __forceinline__ float keyInv(unsigned k){
    unsigned u = (k & 0x80000000u) ? (k & 0x7fffffffu) : ~k;
    return __uint_as_float(u);
}

__global__ void k_init(unsigned* keys, float* zpg){
    int i = threadIdx.x;
    if (i < NCL){ keys[i] = 0xFFFFFFFFu; keys[NCL+i] = 0u; }
    #pragma unroll
    for (int k = 0; k < 4; ++k) zpg[k*64 + i] = 0.f;
}

// ---- Pass A: logit (einsum + bias), softmax masks, per-voxel mean/max over C ----
__global__ __launch_bounds__(256) void k_logit_softmax(
    const float* __restrict__ x, const float* __restrict__ clsw,
    const float* __restrict__ clsb, float* __restrict__ masks,
    float* __restrict__ logit, float* __restrict__ mx, float* __restrict__ Mx)
{
    __shared__ float sw[NCL*CCH];
    __shared__ float sb[NCL];
    int tid = threadIdx.x;
    for (int q = tid; q < NCL*CCH; q += 256) sw[q] = clsw[q];
    if (tid < NCL) sb[tid] = clsb[tid];
    __syncthreads();
    int v = blockIdx.x*256 + tid;
    float acc[NCL];
    #pragma unroll
    for (int o=0;o<NCL;o++) acc[o] = sb[o];
    float s = 0.f, mm = -1e30f;
    for (int c=0;c<CCH;c++){
        float xv = x[c*VOX + v];
        s += xv; mm = fmaxf(mm, xv);
        #pragma unroll
        for (int o=0;o<NCL;o++) acc[o] = fmaf(xv, sw[o*CCH + c], acc[o]);
    }
    mx[v] = s * (1.f/64.f);
    Mx[v] = mm;
    float lm = acc[0];
    #pragma unroll
    for (int o=1;o<NCL;o++) lm = fmaxf(lm, acc[o]);
    float es = 0.f;
    #pragma unroll
    for (int o=0;o<NCL;o++){
        logit[o*VOX + v] = acc[o];
        float e = expf(acc[o] - lm);
        es += e; acc[o] = e;
    }
    float inv = 1.f/es;
    #pragma unroll
    for (int o=0;o<NCL;o++) masks[o*VOX + v] = acc[o]*inv;
}

// ---- Pass B: round-6 geometry + exact vmcnt + fused finalize (no k_heat pass) ----
// block = 128 thr (2 waves): y = tid>>2 (32 rows), x0 = (tid&3)*8 (8 outputs).
// grid = (4 y, 16 z, 20 cls) cls-SLOWEST = 1280 blocks = exactly 5/CU (LDS 30.7KB caps 5).
// Slice = 3 raw planes (mask,mx,Mx) of [40 rows x 32] (rows 0..37 real), plain row-major.
// 15 global_load_lds(16B)/slice: wave0 8, wave1 7; zero-page OOB -> full-EXEC exact counts.
// Finalize: per-thread m/mx saved from LDS while slice resident (3-deep reg pipeline)
// -> sigmoid+heat+minmax+store(ma) in-kernel, zero extra VMEM loads.

#define F8(AL,AH,WV,q0,q1,q2,q3,q4,q5,q6,q7) { \
    AL.x=fmaf(q0,WV,AL.x); AL.y=fmaf(q1,WV,AL.y); AL.z=fmaf(q2,WV,AL.z); AL.w=fmaf(q3,WV,AL.w); \
    AH.x=fmaf(q4,WV,AH.x); AH.y=fmaf(q5,WV,AH.y); AH.z=fmaf(q6,WV,AH.z); AH.w=fmaf(q7,WV,AH.w); }

#define DZ8(AL,AH,WP,P) { \
    F8(AL,AH,(WP)[0], P##1,P##2,P##3,P##4,P##5,P##6,P##7,P##8) \
    F8(AL,AH,(WP)[1], P##2,P##3,P##4,P##5,P##6,P##7,P##8,P##9) \
    F8(AL,AH,(WP)[2], P##3,P##4,P##5,P##6,P##7,P##8,P##9,P##10) \
    F8(AL,AH,(WP)[3], P##4,P##5,P##6,P##7,P##8,P##9,P##10,P##11) \
    F8(AL,AH,(WP)[4], P##5,P##6,P##7,P##8,P##9,P##10,P##11,P##12) \
    F8(AL,AH,(WP)[5], P##6,P##7,P##8,P##9,P##10,P##11,P##12,P##13) \
    F8(AL,AH,(WP)[6], P##7,P##8,P##9,P##10,P##11,P##12,P##13,P##14) }

#define TGROUP(P, WT) { \
    const float* wd_ = (WT) + dy*7; \
    if (ok6) DZ8(a6l,a6h, wd_+0,   P) \
    if (ok5) DZ8(a5l,a5h, wd_+49,  P) \
    if (ok4) DZ8(a4l,a4h, wd_+98,  P) \
    if (ok3) DZ8(a3l,a3h, wd_+147, P) \
    if (ok2) DZ8(a2l,a2h, wd_+196, P) \
    if (ok1) DZ8(a1l,a1h, wd_+245, P) \
    if (ok0) DZ8(a0l,a0h, wd_+294, P) }

#define PLANE_F 1280     // 40 rows x 32 floats
#define BUF_F   3840     // 3 planes
#define LDS_F   7680     // 2 buffers

__device__ __forceinline__ void issue_slice(const float* mk, const float* mxp, const float* Mxp,
        const float* zpg, float* FLf, int bufF, int zi, int y0, int lane, int wid)
{
    const bool zok = (unsigned)zi < (unsigned)DD;
    const float* srcs[3] = { mk, mxp, Mxp };
    #pragma unroll
    for (int k = 0; k < 15; ++k){
        if ((k < 8) != (wid == 0)) continue;     // wave0: 8 issues, wave1: 7
        const int f = k/5, j = k%5;
        int Q   = j*64 + lane;
        int row = Q >> 3, xq = Q & 7;
        int gy  = y0 - 3 + row;
        const float* g;
        if (zok && row < 38 && (unsigned)gy < (unsigned)HH)
            g = srcs[f] + ((size_t)(zi*HH + gy)*32 + xq*4);
        else
            g = zpg + lane*4;
        float* l = FLf + bufF + f*PLANE_F + j*256;   // wave-uniform; HW adds lane*16B
        __builtin_amdgcn_global_load_lds(
            (const __attribute__((address_space(1))) void*)g,
            (__attribute__((address_space(3))) void*)l, 16, 0, 0);
    }
}

__global__ __launch_bounds__(128, 3) void k_conv10(const float* __restrict__ masksAll,
        const float* __restrict__ mxp, const float* __restrict__ Mxp,
        const float* __restrict__ cfr, float* __restrict__ G,
        unsigned* __restrict__ keys, const float* __restrict__ zpg)
{
    __shared__ __align__(16) float FLf[LDS_F];
    __shared__ float r4[4];
    const int y0  = blockIdx.x * 32;
    const int z0  = blockIdx.y * ZT;
    const int cls = blockIdx.z;
    const int tid = threadIdx.x;
    const int lane = tid & 63, wid = tid >> 6;
    const int y  = tid >> 2;          // 0..31
    const int xg = tid & 3;
    const int x0 = xg * 8;
    const bool lo_inv = (xg == 0), hi_inv = (xg == 3);
    const float* mk   = masksAll + (size_t)cls * VOX;
    const float* wcls = cfr + cls*1029;          // uniform -> scalar loads
    float* Gc = G + (size_t)cls * VOX;

    issue_slice(mk, mxp, Mxp, zpg, FLf, 0,     z0-3, y0, lane, wid);
    issue_slice(mk, mxp, Mxp, zpg, FLf, BUF_F, z0-2, y0, lane, wid);

    float4 a0l{},a0h{},a1l{},a1h{},a2l{},a2h{},a3l{},a3h{},
           a4l{},a4h{},a5l{},a5h{},a6l{},a6h{};
    // 3-deep save pipeline of (m, mx) for the thread's 8 output cols
    float4 g0ml{},g0mh{},g0xl{},g0xh{},
           g1ml{},g1mh{},g1xl{},g1xh{},
           g2ml{},g2mh{},g2xl{},g2xh{};
    float hmn = 1e30f, hmx = -1e30f;
    int cur = 0;

    #pragma unroll 1
    for (int zi = z0 - 3; zi <= z0 + ZT + 2; ++zi){
        // exact wait: leave next-slice loads (+2 stores once storing started) in flight
        const bool pst = (zi >= z0 + 4);
        if (wid == 0){ if (pst) asm volatile("s_waitcnt vmcnt(10)" ::: "memory");
                       else     asm volatile("s_waitcnt vmcnt(8)"  ::: "memory"); }
        else         { if (pst) asm volatile("s_waitcnt vmcnt(9)"  ::: "memory");
                       else     asm volatile("s_waitcnt vmcnt(7)"  ::: "memory"); }
        __builtin_amdgcn_sched_barrier(0);
        __builtin_amdgcn_s_barrier();
        __builtin_amdgcn_sched_barrier(0);

        // save this slice's m/mx at the thread's output row/cols (slice resident now)
        float4 nml{}, nmh{}, nxl{}, nxh{};
        if (zi >= z0 && zi < z0 + ZT){
            const float* Pv = FLf + cur*BUF_F + (y+3)*32 + x0;
            nml = *(const float4*)(Pv);
            nmh = *(const float4*)(Pv + 4);
            nxl = *(const float4*)(Pv + PLANE_F);
            nxh = *(const float4*)(Pv + PLANE_F + 4);
        }

        const int lo = z0 + 3 - zi;                // okJ: J>=lo && J-lo<ZT (wave-uniform)
        const bool ok0 = (0>=lo) && (0-lo<ZT);
        const bool ok1 = (1>=lo) && (1-lo<ZT);
        const bool ok2 = (2>=lo) && (2-lo<ZT);
        const bool ok3 = (3>=lo) && (3-lo<ZT);
        const bool ok4 = (4>=lo) && (4-lo<ZT);
        const bool ok5 = (5>=lo) && (5-lo<ZT);
        const bool ok6 = (6>=lo) && (6-lo<ZT);

        __builtin_amdgcn_s_setprio(1);
        #pragma unroll 1
        for (int dy = 0; dy < 7; ++dy){
            const int r = y + dy;
            const float* Pm = FLf + cur*BUF_F + r*32;
            const float* Pa = Pm + PLANE_F;
            const float* Pb = Pa + PLANE_F;
            const int c0 = (xg > 0 ? 2*xg-1 : 0)*4;
            const int c1 = (2*xg)*4;
            const int c2 = (2*xg+1)*4;
            const int c3 = (xg < 3 ? 2*xg+2 : 7)*4;
            const float4 M0 = *(const float4*)(Pm + c0);
            const float4 M1 = *(const float4*)(Pm + c1);
            const float4 M2 = *(const float4*)(Pm + c2);
            const float4 M3 = *(const float4*)(Pm + c3);
            const float pm1 = lo_inv ? 0.f : M0.y;
            const float pm2 = lo_inv ? 0.f : M0.z;
            const float pm3 = lo_inv ? 0.f : M0.w;
            const float pm4 = M1.x, pm5 = M1.y, pm6 = M1.z, pm7 = M1.w;
            const float pm8 = M2.x, pm9 = M2.y, pm10 = M2.z, pm11 = M2.w;
            const float pm12 = hi_inv ? 0.f : M3.x;
            const float pm13 = hi_inv ? 0.f : M3.y;
            const float pm14 = hi_inv ? 0.f : M3.z;

            {   // t = 0: field mask*mx
                const float4 A0 = *(const float4*)(Pa + c0);
                const float4 A1 = *(const float4*)(Pa + c1);
                const float4 A2 = *(const float4*)(Pa + c2);
                const float4 A3 = *(const float4*)(Pa + c3);
                const float pa1 = pm1*A0.y,  pa2 = pm2*A0.z,  pa3 = pm3*A0.w;
                const float pa4 = pm4*A1.x,  pa5 = pm5*A1.y,  pa6 = pm6*A1.z,  pa7 = pm7*A1.w;
                const float pa8 = pm8*A2.x,  pa9 = pm9*A2.y,  pa10 = pm10*A2.z, pa11 = pm11*A2.w;
                const float pa12 = pm12*A3.x, pa13 = pm13*A3.y, pa14 = pm14*A3.z;
                TGROUP(pa, wcls)
            }
            {   // t = 1: field mask*Mx
                const float4 B0 = *(const float4*)(Pb + c0);
                const float4 B1 = *(const float4*)(Pb + c1);
                const float4 B2 = *(const float4*)(Pb + c2);
                const float4 B3 = *(const float4*)(Pb + c3);
                const float pb1 = pm1*B0.y,  pb2 = pm2*B0.z,  pb3 = pm3*B0.w;
                const float pb4 = pm4*B1.x,  pb5 = pm5*B1.y,  pb6 = pm6*B1.z,  pb7 = pm7*B1.w;
                const float pb8 = pm8*B2.x,  pb9 = pm9*B2.y,  pb10 = pm10*B2.z, pb11 = pm11*B2.w;
                const float pb12 = pm12*B3.x, pb13 = pm13*B3.y, pb14 = pm14*B3.z;
                TGROUP(pb, wcls + 343)
            }
            // t = 2: field mask
            TGROUP(pm, wcls + 686)
        }
        __builtin_amdgcn_s_setprio(0);

        __builtin_amdgcn_sched_barrier(0);
        __builtin_amdgcn_s_barrier();            // all waves done reading buf[cur]
        __builtin_amdgcn_sched_barrier(0);
        issue_slice(mk, mxp, Mxp, zpg, FLf, cur*BUF_F, zi+2, y0, lane, wid);
        __builtin_amdgcn_sched_barrier(0);

        if (zi >= z0 + 3){                       // finalize plane zo = zi-3 from saved regs
            const int zo = zi - 3;
            const int oidx = (zo*HH + (y0 + y))*WW + x0;
            float4 r1, r2;
            r1.x = g0ml.x/(1.f + expf(-a0l.x));
            r1.y = g0ml.y/(1.f + expf(-a0l.y));
            r1.z = g0ml.z/(1.f + expf(-a0l.z));
            r1.w = g0ml.w/(1.f + expf(-a0l.w));
            r2.x = g0mh.x/(1.f + expf(-a0h.x));
            r2.y = g0mh.y/(1.f + expf(-a0h.y));
            r2.z = g0mh.z/(1.f + expf(-a0h.z));
            r2.w = g0mh.w/(1.f + expf(-a0h.w));
            *(float4*)(Gc + oidx)     = r1;      // stores AFTER issues (vmcnt order)
            *(float4*)(Gc + oidx + 4) = r2;
            float h0 = r1.x*g0xl.x, h1 = r1.y*g0xl.y, h2 = r1.z*g0xl.z, h3 = r1.w*g0xl.w;
            float h4 = r2.x*g0xh.x, h5 = r2.y*g0xh.y, h6 = r2.z*g0xh.z, h7 = r2.w*g0xh.w;
            hmn = fminf(hmn, fminf(fminf(fminf(h0,h1),fminf(h2,h3)), fminf(fminf(h4,h5),fminf(h6,h7))));
            hmx = fmaxf(hmx, fmaxf(fmaxf(fmaxf(h0,h1),fmaxf(h2,h3)), fmaxf(fmaxf(h4,h5),fmaxf(h6,h7))));
        }
        // rotate accumulators and save pipeline
        a0l=a1l; a0h=a1h; a1l=a2l; a1h=a2h; a2l=a3l; a2h=a3h;
        a3l=a4l; a3h=a4h; a4l=a5l; a4h=a5h; a5l=a6l; a5h=a6h;
        a6l = make_float4(0.f,0.f,0.f,0.f);
        a6h = make_float4(0.f,0.f,0.f,0.f);
        g0ml=g1ml; g0mh=g1mh; g0xl=g1xl; g0xh=g1xh;
        g1ml=g2ml; g1mh=g2mh; g1xl=g2xl; g1xh=g2xh;
        g2ml=nml;  g2mh=nmh;  g2xl=nxl;  g2xh=nxh;
        cur ^= 1;
    }
    asm volatile("s_waitcnt vmcnt(0)" ::: "memory");  // drain dummy DMA before LDS dealloc

    #pragma unroll
    for (int off = 32; off > 0; off >>= 1){
        hmn = fminf(hmn, __shfl_xor(hmn, off));
        hmx = fmaxf(hmx, __shfl_xor(hmx, off));
    }
    if ((tid & 63) == 0){ r4[wid*2] = hmn; r4[wid*2+1] = hmx; }
    __syncthreads();
    if (tid == 0){
        atomicMin(&keys[cls],     keyOf(fminf(r4[0], r4[2])));
        atomicMax(&keys[NCL+cls], keyOf(fmaxf(r4[1], r4[3])));
    }
}

__global__ void k_thr(const unsigned* __restrict__ keys, float* __restrict__ hminA,
                      float* __restrict__ invR){
    int i = threadIdx.x;
    if (i < NCL){
        float hm = keyInv(keys[i]);
        float hM = keyInv(keys[NCL+i]);
        hminA[i] = hm;
        invR[i] = 1.f/(hM - hm);
    }
}

// ---- g = ma * (norm > 0.2), in place ----
__global__ __launch_bounds__(256) void k_region(float* G, const float* __restrict__ mx,
        const float* __restrict__ hminA, const float* __restrict__ invR)
{
    int i = blockIdx.y;
    int v = blockIdx.x*256 + threadIdx.x;
    float ma = G[i*VOX + v];
    float heat = ma * mx[v];
    float norm = (heat - hminA[i]) * invR[i];
    G[i*VOX + v] = (norm > THRESV) ? ma : 0.f;
}

// ---- per-(class,channel) sums S1 = sum x*g, S2 = sum (x*g)^2 ----
__global__ __launch_bounds__(256) void k_stats(const float* __restrict__ x,
        const float* G, float* __restrict__ part)
{
    int tid = threadIdx.x;
    int c = tid & 63, vg = tid >> 6;
    int v0 = blockIdx.x * 2048;
    float s1[NCL], s2[NCL];
    #pragma unroll
    for (int i=0;i<NCL;i++){ s1[i]=0.f; s2[i]=0.f; }
    const float* xc = x + c*VOX;
    for (int k=0;k<512;k++){
        int v = v0 + (k<<2) + vg;
        float xv = xc[v];
        #pragma unroll
        for (int i=0;i<NCL;i++){
            float p = xv * G[i*VOX + v];
            s1[i] += p;
            s2[i] = fmaf(p, p, s2[i]);
        }
    }
    __shared__ float red[4][64][2*NCL];
    #pragma unroll
    for (int i=0;i<NCL;i++){ red[vg][c][i] = s1[i]; red[vg][c][NCL+i] = s2[i]; }
    __syncthreads();
    if (vg == 0){
        float* dst = part + (size_t)blockIdx.x * (NCL*CCH*2);
        for (int i=0;i<NCL;i++){
            float a = red[0][c][i]+red[1][c][i]+red[2][c][i]+red[3][c][i];
            float b = red[0][c][NCL+i]+red[1][c][NCL+i]+red[2][c][NCL+i]+red[3][c][NCL+i];
            dst[i*CCH*2 + c*2 + 0] = a;
            dst[i*CCH*2 + c*2 + 1] = b;
        }
    }
}

// ---- finish stats: a = gamma*rinv, kc = beta - m*rinv*gamma ----
__global__ void k_params(const float* __restrict__ part, const float* __restrict__ gamma,
        const float* __restrict__ beta, float* __restrict__ aArr, float* __restrict__ kcArr)
{
    int i = blockIdx.x, c = threadIdx.x;
    float s1 = 0.f, s2 = 0.f;
    for (int b=0;b<256;b++){
        const float* p = part + (size_t)b*(NCL*CCH*2) + i*CCH*2 + c*2;
        s1 += p[0]; s2 += p[1];
    }
    float m   = s1 * (1.f/(float)VOX);
    float var = s2 * (1.f/(float)VOX) - m*m;
    float rinv = 1.f/sqrtf(var + EPSV);
    float gm = gamma[c];
    aArr[i*CCH + c]  = gm*rinv;
    kcArr[i*CCH + c] = beta[c] - m*rinv*gm;
}

__global__ void k_kcol(const float* __restrict__ kcArr, float* __restrict__ KcA){
    int c = threadIdx.x;
    if (c < CCH){
        float s = 0.f;
        for (int i=0;i<NCL;i++) s += kcArr[i*CCH + c];
        KcA[c] = s;
    }
}

// ---- final: out[c,v] = relu( x*Sum_i g_i*a_ic + K[c] ), in-place over d_out ----
__global__ __launch_bounds__(256) void k_final(const float* __restrict__ x,
        float* outAll, const float* __restrict__ aArr, const float* __restrict__ KcA)
{
    __shared__ float aL[NCL*CCH];
    __shared__ float KL[CCH];
    int tid = threadIdx.x;
    for (int q=tid; q<NCL*CCH; q+=256) aL[q] = aArr[q];
    if (tid < CCH) KL[tid] = KcA[tid];
    __syncthreads();
    int v = blockIdx.x*256 + tid;
    const float* Gp = outAll + (size_t)NCL*VOX;
    float g[NCL];
    #pragma unroll
    for (int i=0;i<NCL;i++) g[i] = Gp[i*VOX + v];
    #pragma unroll 4
    for (int c=0;c<CCH;c++){
        float P = 0.f;
        #pragma unroll
        for (int i=0;i<NCL;i++) P = fmaf(g[i], aL[i*CCH + c], P);
        float xv = x[c*VOX + v];
        outAll[c*VOX + v] = fmaxf(0.f, fmaf(xv, P, KL[c]));
    }
}

extern "C" void kernel_launch(void* const* d_in, const int* in_sizes, int n_in,
                              void* d_out, int out_size, void* d_ws, size_t ws_size,
                              hipStream_t stream)
{
    const float* x     = (const float*)d_in[0];
    const float* clsw  = (const float*)d_in[1];
    const float* clsb  = (const float*)d_in[2];
    const float* cfr   = (const float*)d_in[3];
    const float* gamma = (const float*)d_in[4];
    const float* beta  = (const float*)d_in[5];

    float* out   = (float*)d_out;
    float* logit = out + (size_t)CCH*VOX;     // second output
    float* masks = out;                       // scratch: out[0 .. 20V)
    float* G     = out + (size_t)NCL*VOX;     // scratch: out[20V .. 40V)

    float* ws    = (float*)d_ws;
    float* mxp   = ws;                        // V
    float* Mxp   = ws + VOX;                  // V
    unsigned* keys = (unsigned*)(ws + 2*(size_t)VOX);   // 40
    float* hminA = ws + 2*(size_t)VOX + 64;   // 20
    float* invR  = hminA + NCL;               // 20
    float* part  = ws + 2*(size_t)VOX + 128;  // 256*2560
    float* aArr  = part + 256*(NCL*CCH*2);    // 1280
    float* kcArr = aArr + NCL*CCH;            // 1280
    float* KcA   = kcArr + NCL*CCH;           // 64
    float* zpg   = KcA + CCH;                 // 256 (zero page for OOB lanes)

    k_init<<<1, 64, 0, stream>>>(keys, zpg);
    k_logit_softmax<<<VOX/256, 256, 0, stream>>>(x, clsw, clsb, masks, logit, mxp, Mxp);
    k_conv10<<<dim3(4, 16, NCL), 128, 0, stream>>>(masks, mxp, Mxp, cfr, G, keys, zpg);
    k_thr<<<1, 32, 0, stream>>>(keys, hminA, invR);
    k_region<<<dim3(VOX/256, NCL), 256, 0, stream>>>(G, mxp, hminA, invR);
    k_stats<<<256, 256, 0, stream>>>(x, G, part);
    k_params<<<NCL, CCH, 0, stream>>>(part, gamma, beta, aArr, kcArr);
    k_kcol<<<1, CCH, 0, stream>>>(kcArr, KcA);
    k_final<<<VOX/256, 256, 0, stream>>>(x, out, aArr, KcA);
}

// Round 11
// 764.572 us; speedup vs baseline: 1.4330x; 1.0016x over previous
//
#include <hip/hip_runtime.h>

#define VOX (128*128*32)   // 524288 voxels
#define CCH 64
#define NCL 20
#define DD 128
#define HH 128
#define WW 32
#define ZT 8
#define EPSV 1e-5f
#define THRESV 0.2f

// ---- order-preserving float <-> uint key for atomic min/max ----
__device__ __forceinline__ unsigned keyOf(float f){
    unsigned u = __float_as_uint(f);
    return (u & 0x80000000u) ? ~u : (u | 0x80000000u);
}
__device__ __forceinline__ float keyInv(unsigned k){
    unsigned u = (k & 0x80000000u) ? (k & 0x7fffffffu) : ~k;
    return __uint_as_float(u);
}

__global__ void k_init(unsigned* keys, float* zpg){
    int i = threadIdx.x;
    if (i < NCL){ keys[i] = 0xFFFFFFFFu; keys[NCL+i] = 0u; }
    #pragma unroll
    for (int k = 0; k < 4; ++k) zpg[k*64 + i] = 0.f;
}

// ---- Pass A: logit (einsum + bias), softmax masks, per-voxel mean/max over C ----
__global__ __launch_bounds__(256) void k_logit_softmax(
    const float* __restrict__ x, const float* __restrict__ clsw,
    const float* __restrict__ clsb, float* __restrict__ masks,
    float* __restrict__ logit, float* __restrict__ mx, float* __restrict__ Mx)
{
    __shared__ float sw[NCL*CCH];
    __shared__ float sb[NCL];
    int tid = threadIdx.x;
    for (int q = tid; q < NCL*CCH; q += 256) sw[q] = clsw[q];
    if (tid < NCL) sb[tid] = clsb[tid];
    __syncthreads();
    int v = blockIdx.x*256 + tid;
    float acc[NCL];
    #pragma unroll
    for (int o=0;o<NCL;o++) acc[o] = sb[o];
    float s = 0.f, mm = -1e30f;
    for (int c=0;c<CCH;c++){
        float xv = x[c*VOX + v];
        s += xv; mm = fmaxf(mm, xv);
        #pragma unroll
        for (int o=0;o<NCL;o++) acc[o] = fmaf(xv, sw[o*CCH + c], acc[o]);
    }
    mx[v] = s * (1.f/64.f);
    Mx[v] = mm;
    float lm = acc[0];
    #pragma unroll
    for (int o=1;o<NCL;o++) lm = fmaxf(lm, acc[o]);
    float es = 0.f;
    #pragma unroll
    for (int o=0;o<NCL;o++){
        logit[o*VOX + v] = acc[o];
        float e = expf(acc[o] - lm);
        es += e; acc[o] = e;
    }
    float inv = 1.f/es;
    #pragma unroll
    for (int o=0;o<NCL;o++) masks[o*VOX + v] = acc[o]*inv;
}

// ---- Pass B: 32-row geometry + exact vmcnt + fused finalize, capture-in-loop ----
// block = 128 thr (2 waves): y = tid>>2 (32 rows), x0 = (tid&3)*8 (8 outputs).
// grid = (4 y, 16 z, 20 cls) cls-slowest = 1280 blocks = exactly 5/CU (LDS 30.7KB caps 5).
// Finalize operands (m, mx at the output row) are captured FROM THE dy==3 LOADS of the
// main loop (M1/M2/A1/A2 are exactly m/mx[zi][y0+y][x0..x0+7]) -> zero extra LDS reads,
// no 16-way-conflict capture (round-10's mistake). No setprio (m190: hurts lockstep).
// 15 global_load_lds(16B)/slice: wave0 8, wave1 7; zero-page OOB -> exact counts.

#define F8(AL,AH,WV,q0,q1,q2,q3,q4,q5,q6,q7) { \
    AL.x=fmaf(q0,WV,AL.x); AL.y=fmaf(q1,WV,AL.y); AL.z=fmaf(q2,WV,AL.z); AL.w=fmaf(q3,WV,AL.w); \
    AH.x=fmaf(q4,WV,AH.x); AH.y=fmaf(q5,WV,AH.y); AH.z=fmaf(q6,WV,AH.z); AH.w=fmaf(q7,WV,AH.w); }

#define DZ8(AL,AH,WP,P) { \
    F8(AL,AH,(WP)[0], P##1,P##2,P##3,P##4,P##5,P##6,P##7,P##8) \
    F8(AL,AH,(WP)[1], P##2,P##3,P##4,P##5,P##6,P##7,P##8,P##9) \
    F8(AL,AH,(WP)[2], P##3,P##4,P##5,P##6,P##7,P##8,P##9,P##10) \
    F8(AL,AH,(WP)[3], P##4,P##5,P##6,P##7,P##8,P##9,P##10,P##11) \
    F8(AL,AH,(WP)[4], P##5,P##6,P##7,P##8,P##9,P##10,P##11,P##12) \
    F8(AL,AH,(WP)[5], P##6,P##7,P##8,P##9,P##10,P##11,P##12,P##13) \
    F8(AL,AH,(WP)[6], P##7,P##8,P##9,P##10,P##11,P##12,P##13,P##14) }

#define TGROUP(P, WT) { \
    const float* wd_ = (WT) + dy*7; \
    if (ok6) DZ8(a6l,a6h, wd_+0,   P) \
    if (ok5) DZ8(a5l,a5h, wd_+49,  P) \
    if (ok4) DZ8(a4l,a4h, wd_+98,  P) \
    if (ok3) DZ8(a3l,a3h, wd_+147, P) \
    if (ok2) DZ8(a2l,a2h, wd_+196, P) \
    if (ok1) DZ8(a1l,a1h, wd_+245, P) \
    if (ok0) DZ8(a0l,a0h, wd_+294, P) }

#define PLANE_F 1280     // 40 rows x 32 floats
#define BUF_F   3840     // 3 planes
#define LDS_F   7680     // 2 buffers

__device__ __forceinline__ void issue_slice(const float* mk, const float* mxp, const float* Mxp,
        const float* zpg, float* FLf, int bufF, int zi, int y0, int lane, int wid)
{
    const bool zok = (unsigned)zi < (unsigned)DD;
    const float* srcs[3] = { mk, mxp, Mxp };
    #pragma unroll
    for (int k = 0; k < 15; ++k){
        if ((k < 8) != (wid == 0)) continue;     // wave0: 8 issues, wave1: 7
        const int f = k/5, j = k%5;
        int Q   = j*64 + lane;
        int row = Q >> 3, xq = Q & 7;
        int gy  = y0 - 3 + row;
        const float* g;
        if (zok && row < 38 && (unsigned)gy < (unsigned)HH)
            g = srcs[f] + ((size_t)(zi*HH + gy)*32 + xq*4);
        else
            g = zpg + lane*4;
        float* l = FLf + bufF + f*PLANE_F + j*256;   // wave-uniform; HW adds lane*16B
        __builtin_amdgcn_global_load_lds(
            (const __attribute__((address_space(1))) void*)g,
            (__attribute__((address_space(3))) void*)l, 16, 0, 0);
    }
}

__global__ __launch_bounds__(128, 3) void k_conv11(const float* __restrict__ masksAll,
        const float* __restrict__ mxp, const float* __restrict__ Mxp,
        const float* __restrict__ cfr, float* __restrict__ G,
        unsigned* __restrict__ keys, const float* __restrict__ zpg)
{
    __shared__ __align__(16) float FLf[LDS_F];
    __shared__ float r4[4];
    const int y0  = blockIdx.x * 32;
    const int z0  = blockIdx.y * ZT;
    const int cls = blockIdx.z;
    const int tid = threadIdx.x;
    const int lane = tid & 63, wid = tid >> 6;
    const int y  = tid >> 2;          // 0..31
    const int xg = tid & 3;
    const int x0 = xg * 8;
    const bool lo_inv = (xg == 0), hi_inv = (xg == 3);
    const float* mk   = masksAll + (size_t)cls * VOX;
    const float* wcls = cfr + cls*1029;          // uniform -> scalar loads
    float* Gc = G + (size_t)cls * VOX;

    issue_slice(mk, mxp, Mxp, zpg, FLf, 0,     z0-3, y0, lane, wid);
    issue_slice(mk, mxp, Mxp, zpg, FLf, BUF_F, z0-2, y0, lane, wid);

    float4 a0l{},a0h{},a1l{},a1h{},a2l{},a2h{},a3l{},a3h{},
           a4l{},a4h{},a5l{},a5h{},a6l{},a6h{};
    // 3-deep save pipeline of (m, mx) for the thread's 8 output cols
    float4 g0ml{},g0mh{},g0xl{},g0xh{},
           g1ml{},g1mh{},g1xl{},g1xh{},
           g2ml{},g2mh{},g2xl{},g2xh{};
    float hmn = 1e30f, hmx = -1e30f;
    int cur = 0;

    #pragma unroll 1
    for (int zi = z0 - 3; zi <= z0 + ZT + 2; ++zi){
        // exact wait: leave next-slice loads (+2 stores once storing started) in flight
        const bool pst = (zi >= z0 + 4);
        if (wid == 0){ if (pst) asm volatile("s_waitcnt vmcnt(10)" ::: "memory");
                       else     asm volatile("s_waitcnt vmcnt(8)"  ::: "memory"); }
        else         { if (pst) asm volatile("s_waitcnt vmcnt(9)"  ::: "memory");
                       else     asm volatile("s_waitcnt vmcnt(7)"  ::: "memory"); }
        __builtin_amdgcn_sched_barrier(0);
        __builtin_amdgcn_s_barrier();
        __builtin_amdgcn_sched_barrier(0);

        const bool cap = (zi >= z0 && zi < z0 + ZT);   // capture m/mx for plane zi
        float4 nml{}, nmh{}, nxl{}, nxh{};

        const int lo = z0 + 3 - zi;                // okJ: J>=lo && J-lo<ZT (wave-uniform)
        const bool ok0 = (0>=lo) && (0-lo<ZT);
        const bool ok1 = (1>=lo) && (1-lo<ZT);
        const bool ok2 = (2>=lo) && (2-lo<ZT);
        const bool ok3 = (3>=lo) && (3-lo<ZT);
        const bool ok4 = (4>=lo) && (4-lo<ZT);
        const bool ok5 = (5>=lo) && (5-lo<ZT);
        const bool ok6 = (6>=lo) && (6-lo<ZT);

        #pragma unroll 1
        for (int dy = 0; dy < 7; ++dy){
            const int r = y + dy;
            const float* Pm = FLf + cur*BUF_F + r*32;
            const float* Pa = Pm + PLANE_F;
            const float* Pb = Pa + PLANE_F;
            const int c0 = (xg > 0 ? 2*xg-1 : 0)*4;
            const int c1 = (2*xg)*4;
            const int c2 = (2*xg+1)*4;
            const int c3 = (xg < 3 ? 2*xg+2 : 7)*4;
            const float4 M0 = *(const float4*)(Pm + c0);
            const float4 M1 = *(const float4*)(Pm + c1);
            const float4 M2 = *(const float4*)(Pm + c2);
            const float4 M3 = *(const float4*)(Pm + c3);
            if (cap && dy == 3){ nml = M1; nmh = M2; }   // M1/M2 ARE m[zi][y0+y][x0..x0+7]
            const float pm1 = lo_inv ? 0.f : M0.y;
            const float pm2 = lo_inv ? 0.f : M0.z;
            const float pm3 = lo_inv ? 0.f : M0.w;
            const float pm4 = M1.x, pm5 = M1.y, pm6 = M1.z, pm7 = M1.w;
            const float pm8 = M2.x, pm9 = M2.y, pm10 = M2.z, pm11 = M2.w;
            const float pm12 = hi_inv ? 0.f : M3.x;
            const float pm13 = hi_inv ? 0.f : M3.y;
            const float pm14 = hi_inv ? 0.f : M3.z;

            {   // t = 0: field mask*mx
                const float4 A0 = *(const float4*)(Pa + c0);
                const float4 A1 = *(const float4*)(Pa + c1);
                const float4 A2 = *(const float4*)(Pa + c2);
                const float4 A3 = *(const float4*)(Pa + c3);
                if (cap && dy == 3){ nxl = A1; nxh = A2; }   // A1/A2 ARE mx[...]
                const float pa1 = pm1*A0.y,  pa2 = pm2*A0.z,  pa3 = pm3*A0.w;
                const float pa4 = pm4*A1.x,  pa5 = pm5*A1.y,  pa6 = pm6*A1.z,  pa7 = pm7*A1.w;
                const float pa8 = pm8*A2.x,  pa9 = pm9*A2.y,  pa10 = pm10*A2.z, pa11 = pm11*A2.w;
                const float pa12 = pm12*A3.x, pa13 = pm13*A3.y, pa14 = pm14*A3.z;
                TGROUP(pa, wcls)
            }
            {   // t = 1: field mask*Mx
                const float4 B0 = *(const float4*)(Pb + c0);
                const float4 B1 = *(const float4*)(Pb + c1);
                const float4 B2 = *(const float4*)(Pb + c2);
                const float4 B3 = *(const float4*)(Pb + c3);
                const float pb1 = pm1*B0.y,  pb2 = pm2*B0.z,  pb3 = pm3*B0.w;
                const float pb4 = pm4*B1.x,  pb5 = pm5*B1.y,  pb6 = pm6*B1.z,  pb7 = pm7*B1.w;
                const float pb8 = pm8*B2.x,  pb9 = pm9*B2.y,  pb10 = pm10*B2.z, pb11 = pm11*B2.w;
                const float pb12 = pm12*B3.x, pb13 = pm13*B3.y, pb14 = pm14*B3.z;
                TGROUP(pb, wcls + 343)
            }
            // t = 2: field mask
            TGROUP(pm, wcls + 686)
        }

        __builtin_amdgcn_sched_barrier(0);
        __builtin_amdgcn_s_barrier();            // all waves done reading buf[cur]
        __builtin_amdgcn_sched_barrier(0);
        issue_slice(mk, mxp, Mxp, zpg, FLf, cur*BUF_F, zi+2, y0, lane, wid);
        __builtin_amdgcn_sched_barrier(0);

        if (zi >= z0 + 3){                       // finalize plane zo = zi-3 from saved regs
            const int zo = zi - 3;
            const int oidx = (zo*HH + (y0 + y))*WW + x0;
            float4 r1, r2;
            r1.x = g0ml.x/(1.f + expf(-a0l.x));
            r1.y = g0ml.y/(1.f + expf(-a0l.y));
            r1.z = g0ml.z/(1.f + expf(-a0l.z));
            r1.w = g0ml.w/(1.f + expf(-a0l.w));
            r2.x = g0mh.x/(1.f + expf(-a0h.x));
            r2.y = g0mh.y/(1.f + expf(-a0h.y));
            r2.z = g0mh.z/(1.f + expf(-a0h.z));
            r2.w = g0mh.w/(1.f + expf(-a0h.w));
            *(float4*)(Gc + oidx)     = r1;      // stores AFTER issues (vmcnt order)
            *(float4*)(Gc + oidx + 4) = r2;
            float h0 = r1.x*g0xl.x, h1 = r1.y*g0xl.y, h2 = r1.z*g0xl.z, h3 = r1.w*g0xl.w;
            float h4 = r2.x*g0xh.x, h5 = r2.y*g0xh.y, h6 = r2.z*g0xh.z, h7 = r2.w*g0xh.w;
            hmn = fminf(hmn, fminf(fminf(fminf(h0,h1),fminf(h2,h3)), fminf(fminf(h4,h5),fminf(h6,h7))));
            hmx = fmaxf(hmx, fmaxf(fmaxf(fmaxf(h0,h1),fmaxf(h2,h3)), fmaxf(fmaxf(h4,h5),fmaxf(h6,h7))));
        }
        // rotate accumulators and save pipeline
        a0l=a1l; a0h=a1h; a1l=a2l; a1h=a2h; a2l=a3l; a2h=a3h;
        a3l=a4l; a3h=a4h; a4l=a5l; a4h=a5h; a5l=a6l; a5h=a6h;
        a6l = make_float4(0.f,0.f,0.f,0.f);
        a6h = make_float4(0.f,0.f,0.f,0.f);
        g0ml=g1ml; g0mh=g1mh; g0xl=g1xl; g0xh=g1xh;
        g1ml=g2ml; g1mh=g2mh; g1xl=g2xl; g1xh=g2xh;
        g2ml=nml;  g2mh=nmh;  g2xl=nxl;  g2xh=nxh;
        cur ^= 1;
    }
    asm volatile("s_waitcnt vmcnt(0)" ::: "memory");  // drain dummy DMA before LDS dealloc

    #pragma unroll
    for (int off = 32; off > 0; off >>= 1){
        hmn = fminf(hmn, __shfl_xor(hmn, off));
        hmx = fmaxf(hmx, __shfl_xor(hmx, off));
    }
    if ((tid & 63) == 0){ r4[wid*2] = hmn; r4[wid*2+1] = hmx; }
    __syncthreads();
    if (tid == 0){
        atomicMin(&keys[cls],     keyOf(fminf(r4[0], r4[2])));
        atomicMax(&keys[NCL+cls], keyOf(fmaxf(r4[1], r4[3])));
    }
}

__global__ void k_thr(const unsigned* __restrict__ keys, float* __restrict__ hminA,
                      float* __restrict__ invR){
    int i = threadIdx.x;
    if (i < NCL){
        float hm = keyInv(keys[i]);
        float hM = keyInv(keys[NCL+i]);
        hminA[i] = hm;
        invR[i] = 1.f/(hM - hm);
    }
}

// ---- g = ma * (norm > 0.2), in place ----
__global__ __launch_bounds__(256) void k_region(float* G, const float* __restrict__ mx,
        const float* __restrict__ hminA, const float* __restrict__ invR)
{
    int i = blockIdx.y;
    int v = blockIdx.x*256 + threadIdx.x;
    float ma = G[i*VOX + v];
    float heat = ma * mx[v];
    float norm = (heat - hminA[i]) * invR[i];
    G[i*VOX + v] = (norm > THRESV) ? ma : 0.f;
}

// ---- per-(class,channel) sums S1 = sum x*g, S2 = sum (x*g)^2 ----
__global__ __launch_bounds__(256) void k_stats(const float* __restrict__ x,
        const float* G, float* __restrict__ part)
{
    int tid = threadIdx.x;
    int c = tid & 63, vg = tid >> 6;
    int v0 = blockIdx.x * 2048;
    float s1[NCL], s2[NCL];
    #pragma unroll
    for (int i=0;i<NCL;i++){ s1[i]=0.f; s2[i]=0.f; }
    const float* xc = x + c*VOX;
    for (int k=0;k<512;k++){
        int v = v0 + (k<<2) + vg;
        float xv = xc[v];
        #pragma unroll
        for (int i=0;i<NCL;i++){
            float p = xv * G[i*VOX + v];
            s1[i] += p;
            s2[i] = fmaf(p, p, s2[i]);
        }
    }
    __shared__ float red[4][64][2*NCL];
    #pragma unroll
    for (int i=0;i<NCL;i++){ red[vg][c][i] = s1[i]; red[vg][c][NCL+i] = s2[i]; }
    __syncthreads();
    if (vg == 0){
        float* dst = part + (size_t)blockIdx.x * (NCL*CCH*2);
        for (int i=0;i<NCL;i++){
            float a = red[0][c][i]+red[1][c][i]+red[2][c][i]+red[3][c][i];
            float b = red[0][c][NCL+i]+red[1][c][NCL+i]+red[2][c][NCL+i]+red[3][c][NCL+i];
            dst[i*CCH*2 + c*2 + 0] = a;
            dst[i*CCH*2 + c*2 + 1] = b;
        }
    }
}

// ---- finish stats: a = gamma*rinv, kc = beta - m*rinv*gamma ----
__global__ void k_params(const float* __restrict__ part, const float* __restrict__ gamma,
        const float* __restrict__ beta, float* __restrict__ aArr, float* __restrict__ kcArr)
{
    int i = blockIdx.x, c = threadIdx.x;
    float s1 = 0.f, s2 = 0.f;
    for (int b=0;b<256;b++){
        const float* p = part + (size_t)b*(NCL*CCH*2) + i*CCH*2 + c*2;
        s1 += p[0]; s2 += p[1];
    }
    float m   = s1 * (1.f/(float)VOX);
    float var = s2 * (1.f/(float)VOX) - m*m;
    float rinv = 1.f/sqrtf(var + EPSV);
    float gm = gamma[c];
    aArr[i*CCH + c]  = gm*rinv;
    kcArr[i*CCH + c] = beta[c] - m*rinv*gm;
}

__global__ void k_kcol(const float* __restrict__ kcArr, float* __restrict__ KcA){
    int c = threadIdx.x;
    if (c < CCH){
        float s = 0.f;
        for (int i=0;i<NCL;i++) s += kcArr[i*CCH + c];
        KcA[c] = s;
    }
}

// ---- final: out[c,v] = relu( x*Sum_i g_i*a_ic + K[c] ), in-place over d_out ----
__global__ __launch_bounds__(256) void k_final(const float* __restrict__ x,
        float* outAll, const float* __restrict__ aArr, const float* __restrict__ KcA)
{
    __shared__ float aL[NCL*CCH];
    __shared__ float KL[CCH];
    int tid = threadIdx.x;
    for (int q=tid; q<NCL*CCH; q+=256) aL[q] = aArr[q];
    if (tid < CCH) KL[tid] = KcA[tid];
    __syncthreads();
    int v = blockIdx.x*256 + tid;
    const float* Gp = outAll + (size_t)NCL*VOX;
    float g[NCL];
    #pragma unroll
    for (int i=0;i<NCL;i++) g[i] = Gp[i*VOX + v];
    #pragma unroll 4
    for (int c=0;c<CCH;c++){
        float P = 0.f;
        #pragma unroll
        for (int i=0;i<NCL;i++) P = fmaf(g[i], aL[i*CCH + c], P);
        float xv = x[c*VOX + v];
        outAll[c*VOX + v] = fmaxf(0.f, fmaf(xv, P, KL[c]));
    }
}

extern "C" void kernel_launch(void* const* d_in, const int* in_sizes, int n_in,
                              void* d_out, int out_size, void* d_ws, size_t ws_size,
                              hipStream_t stream)
{
    const float* x     = (const float*)d_in[0];
    const float* clsw  = (const float*)d_in[1];
    const float* clsb  = (const float*)d_in[2];
    const float* cfr   = (const float*)d_in[3];
    const float* gamma = (const float*)d_in[4];
    const float* beta  = (const float*)d_in[5];

    float* out   = (float*)d_out;
    float* logit = out + (size_t)CCH*VOX;     // second output
    float* masks = out;                       // scratch: out[0 .. 20V)
    float* G     = out + (size_t)NCL*VOX;     // scratch: out[20V .. 40V)

    float* ws    = (float*)d_ws;
    float* mxp   = ws;                        // V
    float* Mxp   = ws + VOX;                  // V
    unsigned* keys = (unsigned*)(ws + 2*(size_t)VOX);   // 40
    float* hminA = ws + 2*(size_t)VOX + 64;   // 20
    float* invR  = hminA + NCL;               // 20
    float* part  = ws + 2*(size_t)VOX + 128;  // 256*2560
    float* aArr  = part + 256*(NCL*CCH*2);    // 1280
    float* kcArr = aArr + NCL*CCH;            // 1280
    float* KcA   = kcArr + NCL*CCH;           // 64
    float* zpg   = KcA + CCH;                 // 256 (zero page for OOB lanes)

    k_init<<<1, 64, 0, stream>>>(keys, zpg);
    k_logit_softmax<<<VOX/256, 256, 0, stream>>>(x, clsw, clsb, masks, logit, mxp, Mxp);
    k_conv11<<<dim3(4, 16, NCL), 128, 0, stream>>>(masks, mxp, Mxp, cfr, G, keys, zpg);
    k_thr<<<1, 32, 0, stream>>>(keys, hminA, invR);
    k_region<<<dim3(VOX/256, NCL), 256, 0, stream>>>(G, mxp, hminA, invR);
    k_stats<<<256, 256, 0, stream>>>(x, G, part);
    k_params<<<NCL, CCH, 0, stream>>>(part, gamma, beta, aArr, kcArr);
    k_kcol<<<1, CCH, 0, stream>>>(kcArr, KcA);
    k_final<<<VOX/256, 256, 0, stream>>>(x, out, aArr, KcA);
}

// Round 12
// 745.448 us; speedup vs baseline: 1.4697x; 1.0257x over previous
//
#include <hip/hip_runtime.h>

#define VOX (128*128*32)   // 524288 voxels
#define CCH 64
#define NCL 20
#define DD 128
#define HH 128
#define WW 32
#define ZT 8
#define EPSV 1e-5f
#define THRESV 0.2f

// ---- order-preserving float <-> uint key for atomic min/max ----
__device__ __forceinline__ unsigned keyOf(float f){
    unsigned u = __float_as_uint(f);
    return (u & 0x80000000u) ? ~u : (u | 0x80000000u);
}
__device__ __forceinline__ float keyInv(unsigned k){
    unsigned u = (k & 0x80000000u) ? (k & 0x7fffffffu) : ~k;
    return __uint_as_float(u);
}

__global__ void k_init(unsigned* keys, float* zpg){
    int i = threadIdx.x;
    if (i < NCL){ keys[i] = 0xFFFFFFFFu; keys[NCL+i] = 0u; }
    #pragma unroll
    for (int k = 0; k < 4; ++k) zpg[k*64 + i] = 0.f;
}

// ---- Pass A: logit (einsum + bias), softmax masks, per-voxel mean/max over C ----
__global__ __launch_bounds__(256) void k_logit_softmax(
    const float* __restrict__ x, const float* __restrict__ clsw,
    const float* __restrict__ clsb, float* __restrict__ masks,
    float* __restrict__ logit, float* __restrict__ mx, float* __restrict__ Mx)
{
    __shared__ float sw[NCL*CCH];
    __shared__ float sb[NCL];
    int tid = threadIdx.x;
    for (int q = tid; q < NCL*CCH; q += 256) sw[q] = clsw[q];
    if (tid < NCL) sb[tid] = clsb[tid];
    __syncthreads();
    int v = blockIdx.x*256 + tid;
    float acc[NCL];
    #pragma unroll
    for (int o=0;o<NCL;o++) acc[o] = sb[o];
    float s = 0.f, mm = -1e30f;
    for (int c=0;c<CCH;c++){
        float xv = x[c*VOX + v];
        s += xv; mm = fmaxf(mm, xv);
        #pragma unroll
        for (int o=0;o<NCL;o++) acc[o] = fmaf(xv, sw[o*CCH + c], acc[o]);
    }
    mx[v] = s * (1.f/64.f);
    Mx[v] = mm;
    float lm = acc[0];
    #pragma unroll
    for (int o=1;o<NCL;o++) lm = fmaxf(lm, acc[o]);
    float es = 0.f;
    #pragma unroll
    for (int o=0;o<NCL;o++){
        logit[o*VOX + v] = acc[o];
        float e = expf(acc[o] - lm);
        es += e; acc[o] = e;
    }
    float inv = 1.f/es;
    #pragma unroll
    for (int o=0;o<NCL;o++) masks[o*VOX + v] = acc[o]*inv;
}

// ---- Pass B: 32x32 tile, 4-WAVE blocks (5 waves/SIMD residency), fused finalize ----
// block = 256 thr (4 waves): y = tid>>3 (32 rows), x0 = (tid&7)*4 (4 outputs).
// grid = (4 y, 16 z, 20 cls) = 1280 blocks = 5/CU (LDS-capped) -> 20 waves/CU.
// Staging split 4/4/4/3 issues across waves; exact counted vmcnt (+1 store when pst).
// Finalize operands captured from the dy==3 loads (zero extra LDS reads).

#define F4(A, WV, q0,q1,q2,q3) { A.x=fmaf(q0,WV,A.x); A.y=fmaf(q1,WV,A.y); \
                                 A.z=fmaf(q2,WV,A.z); A.w=fmaf(q3,WV,A.w); }
#define DZ4(A, WP, P) { \
    F4(A,(WP)[0], P##0,P##1,P##2,P##3) \
    F4(A,(WP)[1], P##1,P##2,P##3,P##4) \
    F4(A,(WP)[2], P##2,P##3,P##4,P##5) \
    F4(A,(WP)[3], P##3,P##4,P##5,P##6) \
    F4(A,(WP)[4], P##4,P##5,P##6,P##7) \
    F4(A,(WP)[5], P##5,P##6,P##7,P##8) \
    F4(A,(WP)[6], P##6,P##7,P##8,P##9) }

#define TGROUP4(P, WT) { \
    const float* wd_ = (WT) + dy*7; \
    if (ok6) DZ4(a6, wd_+0,   P) \
    if (ok5) DZ4(a5, wd_+49,  P) \
    if (ok4) DZ4(a4, wd_+98,  P) \
    if (ok3) DZ4(a3, wd_+147, P) \
    if (ok2) DZ4(a2, wd_+196, P) \
    if (ok1) DZ4(a1, wd_+245, P) \
    if (ok0) DZ4(a0, wd_+294, P) }

#define PLANE_F 1280     // 40 rows x 32 floats
#define BUF_F   3840     // 3 planes
#define LDS_F   7680     // 2 buffers

__device__ __forceinline__ void issue_slice(const float* mk, const float* mxp, const float* Mxp,
        const float* zpg, float* FLf, int bufF, int zi, int y0, int lane, int wid)
{
    const bool zok = (unsigned)zi < (unsigned)DD;
    const float* srcs[3] = { mk, mxp, Mxp };
    #pragma unroll
    for (int k = 0; k < 15; ++k){
        if ((k >> 2) != wid) continue;           // waves issue 4/4/4/3
        const int f = k/5, j = k%5;
        int Q   = j*64 + lane;
        int row = Q >> 3, xq = Q & 7;
        int gy  = y0 - 3 + row;
        const float* g;
        if (zok && row < 38 && (unsigned)gy < (unsigned)HH)
            g = srcs[f] + ((size_t)(zi*HH + gy)*32 + xq*4);
        else
            g = zpg + lane*4;
        float* l = FLf + bufF + f*PLANE_F + j*256;   // wave-uniform; HW adds lane*16B
        __builtin_amdgcn_global_load_lds(
            (const __attribute__((address_space(1))) void*)g,
            (__attribute__((address_space(3))) void*)l, 16, 0, 0);
    }
}

__global__ __launch_bounds__(256, 5) void k_conv12(const float* __restrict__ masksAll,
        const float* __restrict__ mxp, const float* __restrict__ Mxp,
        const float* __restrict__ cfr, float* __restrict__ G,
        unsigned* __restrict__ keys, const float* __restrict__ zpg)
{
    __shared__ __align__(16) float FLf[LDS_F];
    __shared__ float r4[8];
    const int y0  = blockIdx.x * 32;
    const int z0  = blockIdx.y * ZT;
    const int cls = blockIdx.z;
    const int tid = threadIdx.x;
    const int lane = tid & 63, wid = tid >> 6;
    const int y  = tid >> 3;          // 0..31
    const int xg = tid & 7;           // 0..7
    const int x0 = xg * 4;
    const bool lo_inv = (xg == 0), hi_inv = (xg == 7);
    const float* mk   = masksAll + (size_t)cls * VOX;
    const float* wcls = cfr + cls*1029;          // uniform -> scalar loads
    float* Gc = G + (size_t)cls * VOX;

    issue_slice(mk, mxp, Mxp, zpg, FLf, 0,     z0-3, y0, lane, wid);
    issue_slice(mk, mxp, Mxp, zpg, FLf, BUF_F, z0-2, y0, lane, wid);

    float4 a0{},a1{},a2{},a3{},a4{},a5{},a6{};
    float4 g0m{},g0x{},g1m{},g1x{},g2m{},g2x{};  // 3-deep (m, mx) capture pipeline
    float hmn = 1e30f, hmx = -1e30f;
    int cur = 0;

    #pragma unroll 1
    for (int zi = z0 - 3; zi <= z0 + ZT + 2; ++zi){
        // exact wait: leave next-slice loads (+1 store once storing started) in flight
        const bool pst = (zi >= z0 + 4);
        if (wid == 3){ if (pst) asm volatile("s_waitcnt vmcnt(4)" ::: "memory");
                       else     asm volatile("s_waitcnt vmcnt(3)" ::: "memory"); }
        else         { if (pst) asm volatile("s_waitcnt vmcnt(5)" ::: "memory");
                       else     asm volatile("s_waitcnt vmcnt(4)" ::: "memory"); }
        __builtin_amdgcn_sched_barrier(0);
        __builtin_amdgcn_s_barrier();
        __builtin_amdgcn_sched_barrier(0);

        const bool cap = (zi >= z0 && zi < z0 + ZT);   // capture m/mx for plane zi
        float4 nm{}, nx{};

        const int lo = z0 + 3 - zi;                // okJ: J>=lo && J-lo<ZT (wave-uniform)
        const bool ok0 = (0>=lo) && (0-lo<ZT);
        const bool ok1 = (1>=lo) && (1-lo<ZT);
        const bool ok2 = (2>=lo) && (2-lo<ZT);
        const bool ok3 = (3>=lo) && (3-lo<ZT);
        const bool ok4 = (4>=lo) && (4-lo<ZT);
        const bool ok5 = (5>=lo) && (5-lo<ZT);
        const bool ok6 = (6>=lo) && (6-lo<ZT);

        #pragma unroll 1
        for (int dy = 0; dy < 7; ++dy){
            const int r = y + dy;
            const float* Pm = FLf + cur*BUF_F + r*32;
            const float* Pa = Pm + PLANE_F;
            const float* Pb = Pa + PLANE_F;
            const int c0 = (xg > 0 ? xg-1 : 0)*4;
            const int c1 = xg*4;
            const int c2 = (xg < 7 ? xg+1 : 7)*4;
            const float4 M0 = *(const float4*)(Pm + c0);
            const float4 M1 = *(const float4*)(Pm + c1);
            const float4 M2 = *(const float4*)(Pm + c2);
            if (cap && dy == 3) nm = M1;            // M1 IS m[zi][y0+y][x0..x0+3]
            const float pm0 = lo_inv ? 0.f : M0.y;
            const float pm1 = lo_inv ? 0.f : M0.z;
            const float pm2 = lo_inv ? 0.f : M0.w;
            const float pm3 = M1.x, pm4 = M1.y, pm5 = M1.z, pm6 = M1.w;
            const float pm7 = hi_inv ? 0.f : M2.x;
            const float pm8 = hi_inv ? 0.f : M2.y;
            const float pm9 = hi_inv ? 0.f : M2.z;

            {   // t = 0: field mask*mx
                const float4 A0 = *(const float4*)(Pa + c0);
                const float4 A1 = *(const float4*)(Pa + c1);
                const float4 A2 = *(const float4*)(Pa + c2);
                if (cap && dy == 3) nx = A1;        // A1 IS mx[...]
                const float pa0 = pm0*A0.y, pa1 = pm1*A0.z, pa2 = pm2*A0.w;
                const float pa3 = pm3*A1.x, pa4 = pm4*A1.y, pa5 = pm5*A1.z, pa6 = pm6*A1.w;
                const float pa7 = pm7*A2.x, pa8 = pm8*A2.y, pa9 = pm9*A2.z;
                TGROUP4(pa, wcls)
            }
            {   // t = 1: field mask*Mx
                const float4 B0 = *(const float4*)(Pb + c0);
                const float4 B1 = *(const float4*)(Pb + c1);
                const float4 B2 = *(const float4*)(Pb + c2);
                const float pb0 = pm0*B0.y, pb1 = pm1*B0.z, pb2 = pm2*B0.w;
                const float pb3 = pm3*B1.x, pb4 = pm4*B1.y, pb5 = pm5*B1.z, pb6 = pm6*B1.w;
                const float pb7 = pm7*B2.x, pb8 = pm8*B2.y, pb9 = pm9*B2.z;
                TGROUP4(pb, wcls + 343)
            }
            // t = 2: field mask
            TGROUP4(pm, wcls + 686)
        }

        __builtin_amdgcn_sched_barrier(0);
        __builtin_amdgcn_s_barrier();            // all waves done reading buf[cur]
        __builtin_amdgcn_sched_barrier(0);
        issue_slice(mk, mxp, Mxp, zpg, FLf, cur*BUF_F, zi+2, y0, lane, wid);
        __builtin_amdgcn_sched_barrier(0);

        if (zi >= z0 + 3){                       // finalize plane zo = zi-3 from saved regs
            const int zo = zi - 3;
            const int oidx = (zo*HH + (y0 + y))*WW + x0;
            float4 r1;
            r1.x = g0m.x/(1.f + expf(-a0.x));
            r1.y = g0m.y/(1.f + expf(-a0.y));
            r1.z = g0m.z/(1.f + expf(-a0.z));
            r1.w = g0m.w/(1.f + expf(-a0.w));
            *(float4*)(Gc + oidx) = r1;          // store AFTER issues (vmcnt order)
            float h0 = r1.x*g0x.x, h1 = r1.y*g0x.y, h2 = r1.z*g0x.z, h3 = r1.w*g0x.w;
            hmn = fminf(hmn, fminf(fminf(h0,h1), fminf(h2,h3)));
            hmx = fmaxf(hmx, fmaxf(fmaxf(h0,h1), fmaxf(h2,h3)));
        }
        // rotate accumulators and capture pipeline
        a0=a1; a1=a2; a2=a3; a3=a4; a4=a5; a5=a6;
        a6 = make_float4(0.f,0.f,0.f,0.f);
        g0m=g1m; g0x=g1x; g1m=g2m; g1x=g2x; g2m=nm; g2x=nx;
        cur ^= 1;
    }
    asm volatile("s_waitcnt vmcnt(0)" ::: "memory");  // drain dummy DMA before LDS dealloc

    #pragma unroll
    for (int off = 32; off > 0; off >>= 1){
        hmn = fminf(hmn, __shfl_xor(hmn, off));
        hmx = fmaxf(hmx, __shfl_xor(hmx, off));
    }
    if ((tid & 63) == 0){ r4[wid*2] = hmn; r4[wid*2+1] = hmx; }
    __syncthreads();
    if (tid == 0){
        float a = fminf(fminf(r4[0],r4[2]), fminf(r4[4],r4[6]));
        float b = fmaxf(fmaxf(r4[1],r4[3]), fmaxf(r4[5],r4[7]));
        atomicMin(&keys[cls],     keyOf(a));
        atomicMax(&keys[NCL+cls], keyOf(b));
    }
}

__global__ void k_thr(const unsigned* __restrict__ keys, float* __restrict__ hminA,
                      float* __restrict__ invR){
    int i = threadIdx.x;
    if (i < NCL){
        float hm = keyInv(keys[i]);
        float hM = keyInv(keys[NCL+i]);
        hminA[i] = hm;
        invR[i] = 1.f/(hM - hm);
    }
}

// ---- g = ma * (norm > 0.2), in place ----
__global__ __launch_bounds__(256) void k_region(float* G, const float* __restrict__ mx,
        const float* __restrict__ hminA, const float* __restrict__ invR)
{
    int i = blockIdx.y;
    int v = blockIdx.x*256 + threadIdx.x;
    float ma = G[i*VOX + v];
    float heat = ma * mx[v];
    float norm = (heat - hminA[i]) * invR[i];
    G[i*VOX + v] = (norm > THRESV) ? ma : 0.f;
}

// ---- per-(class,channel) sums S1 = sum x*g, S2 = sum (x*g)^2 ----
// x staged through LDS (coalesced float4 global reads, transposed v-major store) --
// replaces the 64-distinct-cacheline-per-instruction gather of lane=c direct reads.
// Summation order identical to the direct version (bitwise-same results).
__global__ __launch_bounds__(256) void k_stats(const float* __restrict__ x,
        const float* G, float* __restrict__ part)
{
    __shared__ float xt[64][65];   // v-major: xt[vv][c]; row stride 65 -> conflict-free
    int tid = threadIdx.x;
    int c = tid & 63, vg = tid >> 6;
    int v0 = blockIdx.x * 2048;
    const int cc = tid >> 2;        // staging source row (channel) 0..63
    const int u0 = (tid & 3) * 16;  // staging v-group
    float s1[NCL], s2[NCL];
    #pragma unroll
    for (int i=0;i<NCL;i++){ s1[i]=0.f; s2[i]=0.f; }
    #pragma unroll 1
    for (int t = 0; t < 32; ++t){
        int vb = v0 + t*64;
        __syncthreads();            // previous tile fully consumed
        float ld[16];
        #pragma unroll
        for (int j = 0; j < 4; ++j){
            float4 f4 = *(const float4*)&x[(size_t)cc*VOX + vb + u0 + j*4];
            ld[j*4+0]=f4.x; ld[j*4+1]=f4.y; ld[j*4+2]=f4.z; ld[j*4+3]=f4.w;
        }
        #pragma unroll
        for (int j = 0; j < 16; ++j) xt[u0 + j][cc] = ld[j];   // transpose store, 2-way max
        __syncthreads();
        #pragma unroll 1
        for (int k = 0; k < 16; ++k){
            int vv = (k<<2) + vg;   // v = vb + 4k + vg (same order as before)
            float xv = xt[vv][c];
            #pragma unroll
            for (int i=0;i<NCL;i++){
                float p = xv * G[i*VOX + vb + vv];
                s1[i] += p;
                s2[i] = fmaf(p, p, s2[i]);
            }
        }
    }
    __shared__ float red[4][64][2*NCL];
    #pragma unroll
    for (int i=0;i<NCL;i++){ red[vg][c][i] = s1[i]; red[vg][c][NCL+i] = s2[i]; }
    __syncthreads();
    if (vg == 0){
        float* dst = part + (size_t)blockIdx.x * (NCL*CCH*2);
        for (int i=0;i<NCL;i++){
            float a = red[0][c][i]+red[1][c][i]+red[2][c][i]+red[3][c][i];
            float b = red[0][c][NCL+i]+red[1][c][NCL+i]+red[2][c][NCL+i]+red[3][c][NCL+i];
            dst[i*CCH*2 + c*2 + 0] = a;
            dst[i*CCH*2 + c*2 + 1] = b;
        }
    }
}

// ---- finish stats: a = gamma*rinv, kc = beta - m*rinv*gamma ----
__global__ void k_params(const float* __restrict__ part, const float* __restrict__ gamma,
        const float* __restrict__ beta, float* __restrict__ aArr, float* __restrict__ kcArr)
{
    int i = blockIdx.x, c = threadIdx.x;
    float s1 = 0.f, s2 = 0.f;
    for (int b=0;b<256;b++){
        const float* p = part + (size_t)b*(NCL*CCH*2) + i*CCH*2 + c*2;
        s1 += p[0]; s2 += p[1];
    }
    float m   = s1 * (1.f/(float)VOX);
    float var = s2 * (1.f/(float)VOX) - m*m;
    float rinv = 1.f/sqrtf(var + EPSV);
    float gm = gamma[c];
    aArr[i*CCH + c]  = gm*rinv;
    kcArr[i*CCH + c] = beta[c] - m*rinv*gm;
}

__global__ void k_kcol(const float* __restrict__ kcArr, float* __restrict__ KcA){
    int c = threadIdx.x;
    if (c < CCH){
        float s = 0.f;
        for (int i=0;i<NCL;i++) s += kcArr[i*CCH + c];
        KcA[c] = s;
    }
}

// ---- final: out[c,v] = relu( x*Sum_i g_i*a_ic + K[c] ), in-place over d_out ----
__global__ __launch_bounds__(256) void k_final(const float* __restrict__ x,
        float* outAll, const float* __restrict__ aArr, const float* __restrict__ KcA)
{
    __shared__ float aL[NCL*CCH];
    __shared__ float KL[CCH];
    int tid = threadIdx.x;
    for (int q=tid; q<NCL*CCH; q+=256) aL[q] = aArr[q];
    if (tid < CCH) KL[tid] = KcA[tid];
    __syncthreads();
    int v = blockIdx.x*256 + tid;
    const float* Gp = outAll + (size_t)NCL*VOX;
    float g[NCL];
    #pragma unroll
    for (int i=0;i<NCL;i++) g[i] = Gp[i*VOX + v];
    #pragma unroll 4
    for (int c=0;c<CCH;c++){
        float P = 0.f;
        #pragma unroll
        for (int i=0;i<NCL;i++) P = fmaf(g[i], aL[i*CCH + c], P);
        float xv = x[c*VOX + v];
        outAll[c*VOX + v] = fmaxf(0.f, fmaf(xv, P, KL[c]));
    }
}

extern "C" void kernel_launch(void* const* d_in, const int* in_sizes, int n_in,
                              void* d_out, int out_size, void* d_ws, size_t ws_size,
                              hipStream_t stream)
{
    const float* x     = (const float*)d_in[0];
    const float* clsw  = (const float*)d_in[1];
    const float* clsb  = (const float*)d_in[2];
    const float* cfr   = (const float*)d_in[3];
    const float* gamma = (const float*)d_in[4];
    const float* beta  = (const float*)d_in[5];

    float* out   = (float*)d_out;
    float* logit = out + (size_t)CCH*VOX;     // second output
    float* masks = out;                       // scratch: out[0 .. 20V)
    float* G     = out + (size_t)NCL*VOX;     // scratch: out[20V .. 40V)

    float* ws    = (float*)d_ws;
    float* mxp   = ws;                        // V
    float* Mxp   = ws + VOX;                  // V
    unsigned* keys = (unsigned*)(ws + 2*(size_t)VOX);   // 40
    float* hminA = ws + 2*(size_t)VOX + 64;   // 20
    float* invR  = hminA + NCL;               // 20
    float* part  = ws + 2*(size_t)VOX + 128;  // 256*2560
    float* aArr  = part + 256*(NCL*CCH*2);    // 1280
    float* kcArr = aArr + NCL*CCH;            // 1280
    float* KcA   = kcArr + NCL*CCH;           // 64
    float* zpg   = KcA + CCH;                 // 256 (zero page for OOB lanes)

    k_init<<<1, 64, 0, stream>>>(keys, zpg);
    k_logit_softmax<<<VOX/256, 256, 0, stream>>>(x, clsw, clsb, masks, logit, mxp, Mxp);
    k_conv12<<<dim3(4, 16, NCL), 256, 0, stream>>>(masks, mxp, Mxp, cfr, G, keys, zpg);
    k_thr<<<1, 32, 0, stream>>>(keys, hminA, invR);
    k_region<<<dim3(VOX/256, NCL), 256, 0, stream>>>(G, mxp, hminA, invR);
    k_stats<<<256, 256, 0, stream>>>(x, G, part);
    k_params<<<NCL, CCH, 0, stream>>>(part, gamma, beta, aArr, kcArr);
    k_kcol<<<1, CCH, 0, stream>>>(kcArr, KcA);
    k_final<<<VOX/256, 256, 0, stream>>>(x, out, aArr, KcA);
}

// Round 13
// 643.749 us; speedup vs baseline: 1.7019x; 1.1580x over previous
//
#include <hip/hip_runtime.h>

#define VOX (128*128*32)   // 524288 voxels
#define CCH 64
#define NCL 20
#define DD 128
#define HH 128
#define WW 32
#define ZT 8
#define EPSV 1e-5f
#define THRESV 0.2f

// ---- order-preserving float <-> uint key for atomic min/max ----
__device__ __forceinline__ unsigned keyOf(float f){
    unsigned u = __float_as_uint(f);
    return (u & 0x80000000u) ? ~u : (u | 0x80000000u);
}
__device__ __forceinline__ float keyInv(unsigned k){
    unsigned u = (k & 0x80000000u) ? (k & 0x7fffffffu) : ~k;
    return __uint_as_float(u);
}

__global__ void k_init(unsigned* keys, float* zpg){
    int i = threadIdx.x;
    if (i < NCL){ keys[i] = 0xFFFFFFFFu; keys[NCL+i] = 0u; }
    #pragma unroll
    for (int k = 0; k < 4; ++k) zpg[k*64 + i] = 0.f;
}

// ---- Pass A: logit + softmax + per-voxel mean/max, 4 voxels/thread (float4) ----
__global__ __launch_bounds__(256, 4) void k_logit_softmax(
    const float* __restrict__ x, const float* __restrict__ clsw,
    const float* __restrict__ clsb, float* __restrict__ masks,
    float* __restrict__ logit, float* __restrict__ mx, float* __restrict__ Mx)
{
    __shared__ float sw[NCL*CCH];
    __shared__ float sb[NCL];
    int tid = threadIdx.x;
    for (int q = tid; q < NCL*CCH; q += 256) sw[q] = clsw[q];
    if (tid < NCL) sb[tid] = clsb[tid];
    __syncthreads();
    const int v = blockIdx.x*1024 + tid*4;
    float4 acc[NCL];
    #pragma unroll
    for (int o=0;o<NCL;o++){ float b = sb[o]; acc[o] = make_float4(b,b,b,b); }
    float4 s  = make_float4(0.f,0.f,0.f,0.f);
    float4 mm = make_float4(-1e30f,-1e30f,-1e30f,-1e30f);
    for (int c=0;c<CCH;c++){
        float4 xv = *(const float4*)&x[(size_t)c*VOX + v];
        s.x += xv.x; s.y += xv.y; s.z += xv.z; s.w += xv.w;
        mm.x = fmaxf(mm.x, xv.x); mm.y = fmaxf(mm.y, xv.y);
        mm.z = fmaxf(mm.z, xv.z); mm.w = fmaxf(mm.w, xv.w);
        #pragma unroll
        for (int o=0;o<NCL;o++){
            float w = sw[o*CCH + c];
            acc[o].x = fmaf(xv.x, w, acc[o].x);
            acc[o].y = fmaf(xv.y, w, acc[o].y);
            acc[o].z = fmaf(xv.z, w, acc[o].z);
            acc[o].w = fmaf(xv.w, w, acc[o].w);
        }
    }
    *(float4*)&mx[v] = make_float4(s.x*(1.f/64.f), s.y*(1.f/64.f), s.z*(1.f/64.f), s.w*(1.f/64.f));
    *(float4*)&Mx[v] = mm;
    float4 lm = acc[0];
    #pragma unroll
    for (int o=1;o<NCL;o++){
        lm.x = fmaxf(lm.x, acc[o].x); lm.y = fmaxf(lm.y, acc[o].y);
        lm.z = fmaxf(lm.z, acc[o].z); lm.w = fmaxf(lm.w, acc[o].w);
    }
    float4 es = make_float4(0.f,0.f,0.f,0.f);
    #pragma unroll
    for (int o=0;o<NCL;o++){
        *(float4*)&logit[(size_t)o*VOX + v] = acc[o];
        float4 e;
        e.x = expf(acc[o].x - lm.x); e.y = expf(acc[o].y - lm.y);
        e.z = expf(acc[o].z - lm.z); e.w = expf(acc[o].w - lm.w);
        es.x += e.x; es.y += e.y; es.z += e.z; es.w += e.w;
        acc[o] = e;
    }
    float4 inv = make_float4(1.f/es.x, 1.f/es.y, 1.f/es.z, 1.f/es.w);
    #pragma unroll
    for (int o=0;o<NCL;o++){
        float4 r;
        r.x = acc[o].x*inv.x; r.y = acc[o].y*inv.y;
        r.z = acc[o].z*inv.z; r.w = acc[o].w*inv.w;
        *(float4*)&masks[(size_t)o*VOX + v] = r;
    }
}

// ---- Pass B: 32x32 tile, 4-wave blocks, fused finalize, + setprio on FMA body ----
#define F4(A, WV, q0,q1,q2,q3) { A.x=fmaf(q0,WV,A.x); A.y=fmaf(q1,WV,A.y); \
                                 A.z=fmaf(q2,WV,A.z); A.w=fmaf(q3,WV,A.w); }
#define DZ4(A, WP, P) { \
    F4(A,(WP)[0], P##0,P##1,P##2,P##3) \
    F4(A,(WP)[1], P##1,P##2,P##3,P##4) \
    F4(A,(WP)[2], P##2,P##3,P##4,P##5) \
    F4(A,(WP)[3], P##3,P##4,P##5,P##6) \
    F4(A,(WP)[4], P##4,P##5,P##6,P##7) \
    F4(A,(WP)[5], P##5,P##6,P##7,P##8) \
    F4(A,(WP)[6], P##6,P##7,P##8,P##9) }

#define TGROUP4(P, WT) { \
    const float* wd_ = (WT) + dy*7; \
    if (ok6) DZ4(a6, wd_+0,   P) \
    if (ok5) DZ4(a5, wd_+49,  P) \
    if (ok4) DZ4(a4, wd_+98,  P) \
    if (ok3) DZ4(a3, wd_+147, P) \
    if (ok2) DZ4(a2, wd_+196, P) \
    if (ok1) DZ4(a1, wd_+245, P) \
    if (ok0) DZ4(a0, wd_+294, P) }

#define PLANE_F 1280     // 40 rows x 32 floats
#define BUF_F   3840     // 3 planes
#define LDS_F   7680     // 2 buffers

__device__ __forceinline__ void issue_slice(const float* mk, const float* mxp, const float* Mxp,
        const float* zpg, float* FLf, int bufF, int zi, int y0, int lane, int wid)
{
    const bool zok = (unsigned)zi < (unsigned)DD;
    const float* srcs[3] = { mk, mxp, Mxp };
    #pragma unroll
    for (int k = 0; k < 15; ++k){
        if ((k >> 2) != wid) continue;           // waves issue 4/4/4/3
        const int f = k/5, j = k%5;
        int Q   = j*64 + lane;
        int row = Q >> 3, xq = Q & 7;
        int gy  = y0 - 3 + row;
        const float* g;
        if (zok && row < 38 && (unsigned)gy < (unsigned)HH)
            g = srcs[f] + ((size_t)(zi*HH + gy)*32 + xq*4);
        else
            g = zpg + lane*4;
        float* l = FLf + bufF + f*PLANE_F + j*256;   // wave-uniform; HW adds lane*16B
        __builtin_amdgcn_global_load_lds(
            (const __attribute__((address_space(1))) void*)g,
            (__attribute__((address_space(3))) void*)l, 16, 0, 0);
    }
}

__global__ __launch_bounds__(256, 5) void k_conv13(const float* __restrict__ masksAll,
        const float* __restrict__ mxp, const float* __restrict__ Mxp,
        const float* __restrict__ cfr, float* __restrict__ G,
        unsigned* __restrict__ keys, const float* __restrict__ zpg)
{
    __shared__ __align__(16) float FLf[LDS_F];
    __shared__ float r4[8];
    const int y0  = blockIdx.x * 32;
    const int z0  = blockIdx.y * ZT;
    const int cls = blockIdx.z;
    const int tid = threadIdx.x;
    const int lane = tid & 63, wid = tid >> 6;
    const int y  = tid >> 3;          // 0..31
    const int xg = tid & 7;           // 0..7
    const int x0 = xg * 4;
    const bool lo_inv = (xg == 0), hi_inv = (xg == 7);
    const float* mk   = masksAll + (size_t)cls * VOX;
    const float* wcls = cfr + cls*1029;          // uniform -> scalar loads
    float* Gc = G + (size_t)cls * VOX;

    issue_slice(mk, mxp, Mxp, zpg, FLf, 0,     z0-3, y0, lane, wid);
    issue_slice(mk, mxp, Mxp, zpg, FLf, BUF_F, z0-2, y0, lane, wid);

    float4 a0{},a1{},a2{},a3{},a4{},a5{},a6{};
    float4 g0m{},g0x{},g1m{},g1x{},g2m{},g2x{};  // 3-deep (m, mx) capture pipeline
    float hmn = 1e30f, hmx = -1e30f;
    int cur = 0;

    #pragma unroll 1
    for (int zi = z0 - 3; zi <= z0 + ZT + 2; ++zi){
        // exact wait: leave next-slice loads (+1 store once storing started) in flight
        const bool pst = (zi >= z0 + 4);
        if (wid == 3){ if (pst) asm volatile("s_waitcnt vmcnt(4)" ::: "memory");
                       else     asm volatile("s_waitcnt vmcnt(3)" ::: "memory"); }
        else         { if (pst) asm volatile("s_waitcnt vmcnt(5)" ::: "memory");
                       else     asm volatile("s_waitcnt vmcnt(4)" ::: "memory"); }
        __builtin_amdgcn_sched_barrier(0);
        __builtin_amdgcn_s_barrier();
        __builtin_amdgcn_sched_barrier(0);

        const bool cap = (zi >= z0 && zi < z0 + ZT);   // capture m/mx for plane zi
        float4 nm{}, nx{};

        const int lo = z0 + 3 - zi;                // okJ: J>=lo && J-lo<ZT (wave-uniform)
        const bool ok0 = (0>=lo) && (0-lo<ZT);
        const bool ok1 = (1>=lo) && (1-lo<ZT);
        const bool ok2 = (2>=lo) && (2-lo<ZT);
        const bool ok3 = (3>=lo) && (3-lo<ZT);
        const bool ok4 = (4>=lo) && (4-lo<ZT);
        const bool ok5 = (5>=lo) && (5-lo<ZT);
        const bool ok6 = (6>=lo) && (6-lo<ZT);

        __builtin_amdgcn_s_setprio(1);
        #pragma unroll 1
        for (int dy = 0; dy < 7; ++dy){
            const int r = y + dy;
            const float* Pm = FLf + cur*BUF_F + r*32;
            const float* Pa = Pm + PLANE_F;
            const float* Pb = Pa + PLANE_F;
            const int c0 = (xg > 0 ? xg-1 : 0)*4;
            const int c1 = xg*4;
            const int c2 = (xg < 7 ? xg+1 : 7)*4;
            const float4 M0 = *(const float4*)(Pm + c0);
            const float4 M1 = *(const float4*)(Pm + c1);
            const float4 M2 = *(const float4*)(Pm + c2);
            if (cap && dy == 3) nm = M1;            // M1 IS m[zi][y0+y][x0..x0+3]
            const float pm0 = lo_inv ? 0.f : M0.y;
            const float pm1 = lo_inv ? 0.f : M0.z;
            const float pm2 = lo_inv ? 0.f : M0.w;
            const float pm3 = M1.x, pm4 = M1.y, pm5 = M1.z, pm6 = M1.w;
            const float pm7 = hi_inv ? 0.f : M2.x;
            const float pm8 = hi_inv ? 0.f : M2.y;
            const float pm9 = hi_inv ? 0.f : M2.z;

            {   // t = 0: field mask*mx
                const float4 A0 = *(const float4*)(Pa + c0);
                const float4 A1 = *(const float4*)(Pa + c1);
                const float4 A2 = *(const float4*)(Pa + c2);
                if (cap && dy == 3) nx = A1;        // A1 IS mx[...]
                const float pa0 = pm0*A0.y, pa1 = pm1*A0.z, pa2 = pm2*A0.w;
                const float pa3 = pm3*A1.x, pa4 = pm4*A1.y, pa5 = pm5*A1.z, pa6 = pm6*A1.w;
                const float pa7 = pm7*A2.x, pa8 = pm8*A2.y, pa9 = pm9*A2.z;
                TGROUP4(pa, wcls)
            }
            {   // t = 1: field mask*Mx
                const float4 B0 = *(const float4*)(Pb + c0);
                const float4 B1 = *(const float4*)(Pb + c1);
                const float4 B2 = *(const float4*)(Pb + c2);
                const float pb0 = pm0*B0.y, pb1 = pm1*B0.z, pb2 = pm2*B0.w;
                const float pb3 = pm3*B1.x, pb4 = pm4*B1.y, pb5 = pm5*B1.z, pb6 = pm6*B1.w;
                const float pb7 = pm7*B2.x, pb8 = pm8*B2.y, pb9 = pm9*B2.z;
                TGROUP4(pb, wcls + 343)
            }
            // t = 2: field mask
            TGROUP4(pm, wcls + 686)
        }
        __builtin_amdgcn_s_setprio(0);

        __builtin_amdgcn_sched_barrier(0);
        __builtin_amdgcn_s_barrier();            // all waves done reading buf[cur]
        __builtin_amdgcn_sched_barrier(0);
        issue_slice(mk, mxp, Mxp, zpg, FLf, cur*BUF_F, zi+2, y0, lane, wid);
        __builtin_amdgcn_sched_barrier(0);

        if (zi >= z0 + 3){                       // finalize plane zo = zi-3 from saved regs
            const int zo = zi - 3;
            const int oidx = (zo*HH + (y0 + y))*WW + x0;
            float4 r1;
            r1.x = g0m.x/(1.f + expf(-a0.x));
            r1.y = g0m.y/(1.f + expf(-a0.y));
            r1.z = g0m.z/(1.f + expf(-a0.z));
            r1.w = g0m.w/(1.f + expf(-a0.w));
            *(float4*)(Gc + oidx) = r1;          // store AFTER issues (vmcnt order)
            float h0 = r1.x*g0x.x, h1 = r1.y*g0x.y, h2 = r1.z*g0x.z, h3 = r1.w*g0x.w;
            hmn = fminf(hmn, fminf(fminf(h0,h1), fminf(h2,h3)));
            hmx = fmaxf(hmx, fmaxf(fmaxf(h0,h1), fmaxf(h2,h3)));
        }
        // rotate accumulators and capture pipeline
        a0=a1; a1=a2; a2=a3; a3=a4; a4=a5; a5=a6;
        a6 = make_float4(0.f,0.f,0.f,0.f);
        g0m=g1m; g0x=g1x; g1m=g2m; g1x=g2x; g2m=nm; g2x=nx;
        cur ^= 1;
    }
    asm volatile("s_waitcnt vmcnt(0)" ::: "memory");  // drain dummy DMA before LDS dealloc

    #pragma unroll
    for (int off = 32; off > 0; off >>= 1){
        hmn = fminf(hmn, __shfl_xor(hmn, off));
        hmx = fmaxf(hmx, __shfl_xor(hmx, off));
    }
    if ((tid & 63) == 0){ r4[wid*2] = hmn; r4[wid*2+1] = hmx; }
    __syncthreads();
    if (tid == 0){
        float a = fminf(fminf(r4[0],r4[2]), fminf(r4[4],r4[6]));
        float b = fmaxf(fmaxf(r4[1],r4[3]), fmaxf(r4[5],r4[7]));
        atomicMin(&keys[cls],     keyOf(a));
        atomicMax(&keys[NCL+cls], keyOf(b));
    }
}

__global__ void k_thr(const unsigned* __restrict__ keys, float* __restrict__ hminA,
                      float* __restrict__ invR){
    int i = threadIdx.x;
    if (i < NCL){
        float hm = keyInv(keys[i]);
        float hM = keyInv(keys[NCL+i]);
        hminA[i] = hm;
        invR[i] = 1.f/(hM - hm);
    }
}

// ---- g = ma * (norm > 0.2), in place ----
__global__ __launch_bounds__(256) void k_region(float* G, const float* __restrict__ mx,
        const float* __restrict__ hminA, const float* __restrict__ invR)
{
    int i = blockIdx.y;
    int v = blockIdx.x*256 + threadIdx.x;
    float ma = G[i*VOX + v];
    float heat = ma * mx[v];
    float norm = (heat - hminA[i]) * invR[i];
    G[i*VOX + v] = (norm > THRESV) ? ma : 0.f;
}

// ---- per-(class,channel) sums; 512 blocks (2/CU), x staged via LDS transpose ----
__global__ __launch_bounds__(256) void k_stats(const float* __restrict__ x,
        const float* G, float* __restrict__ part)
{
    __shared__ float xt[64][65];
    int tid = threadIdx.x;
    int c = tid & 63, vg = tid >> 6;
    int v0 = blockIdx.x * 1024;
    const int cc = tid >> 2;
    const int u0 = (tid & 3) * 16;
    float s1[NCL], s2[NCL];
    #pragma unroll
    for (int i=0;i<NCL;i++){ s1[i]=0.f; s2[i]=0.f; }
    #pragma unroll 1
    for (int t = 0; t < 16; ++t){
        int vb = v0 + t*64;
        __syncthreads();
        float ld[16];
        #pragma unroll
        for (int j = 0; j < 4; ++j){
            float4 f4 = *(const float4*)&x[(size_t)cc*VOX + vb + u0 + j*4];
            ld[j*4+0]=f4.x; ld[j*4+1]=f4.y; ld[j*4+2]=f4.z; ld[j*4+3]=f4.w;
        }
        #pragma unroll
        for (int j = 0; j < 16; ++j) xt[u0 + j][cc] = ld[j];
        __syncthreads();
        #pragma unroll 1
        for (int k = 0; k < 16; ++k){
            int vv = (k<<2) + vg;
            float xv = xt[vv][c];
            #pragma unroll
            for (int i=0;i<NCL;i++){
                float p = xv * G[i*VOX + vb + vv];
                s1[i] += p;
                s2[i] = fmaf(p, p, s2[i]);
            }
        }
    }
    __shared__ float red[4][64][2*NCL];
    #pragma unroll
    for (int i=0;i<NCL;i++){ red[vg][c][i] = s1[i]; red[vg][c][NCL+i] = s2[i]; }
    __syncthreads();
    if (vg == 0){
        float* dst = part + (size_t)blockIdx.x * (NCL*CCH*2);
        for (int i=0;i<NCL;i++){
            float a = red[0][c][i]+red[1][c][i]+red[2][c][i]+red[3][c][i];
            float b = red[0][c][NCL+i]+red[1][c][NCL+i]+red[2][c][NCL+i]+red[3][c][NCL+i];
            dst[i*CCH*2 + c*2 + 0] = a;
            dst[i*CCH*2 + c*2 + 1] = b;
        }
    }
}

// ---- finish stats over 512 partials (r8-proven 64-thread form) ----
__global__ void k_params(const float* __restrict__ part, const float* __restrict__ gamma,
        const float* __restrict__ beta, float* __restrict__ aArr, float* __restrict__ kcArr)
{
    int i = blockIdx.x, c = threadIdx.x;
    float s1 = 0.f, s2 = 0.f;
    for (int b=0;b<512;b++){
        const float* p = part + (size_t)b*(NCL*CCH*2) + i*CCH*2 + c*2;
        s1 += p[0]; s2 += p[1];
    }
    float m   = s1 * (1.f/(float)VOX);
    float var = s2 * (1.f/(float)VOX) - m*m;
    float rinv = 1.f/sqrtf(var + EPSV);
    float gm = gamma[c];
    aArr[i*CCH + c]  = gm*rinv;
    kcArr[i*CCH + c] = beta[c] - m*rinv*gm;
}

__global__ void k_kcol(const float* __restrict__ kcArr, float* __restrict__ KcA){
    int c = threadIdx.x;
    if (c < CCH){
        float s = 0.f;
        for (int i=0;i<NCL;i++) s += kcArr[i*CCH + c];
        KcA[c] = s;
    }
}

// ---- final: 2 voxels/thread (halves aL broadcast ds_reads per FMA) ----
__global__ __launch_bounds__(256) void k_final(const float* __restrict__ x,
        float* outAll, const float* __restrict__ aArr, const float* __restrict__ KcA)
{
    __shared__ float aL[NCL*CCH];
    __shared__ float KL[CCH];
    int tid = threadIdx.x;
    for (int q=tid; q<NCL*CCH; q+=256) aL[q] = aArr[q];
    if (tid < CCH) KL[tid] = KcA[tid];
    __syncthreads();
    int v = blockIdx.x*512 + tid;     // voxels v and v+256
    const float* Gp = outAll + (size_t)NCL*VOX;
    float g[NCL], h[NCL];
    #pragma unroll
    for (int i=0;i<NCL;i++){ g[i] = Gp[i*VOX + v]; h[i] = Gp[i*VOX + v + 256]; }
    #pragma unroll 4
    for (int c=0;c<CCH;c++){
        float P0 = 0.f, P1 = 0.f;
        #pragma unroll
        for (int i=0;i<NCL;i++){
            float a = aL[i*CCH + c];
            P0 = fmaf(g[i], a, P0);
            P1 = fmaf(h[i], a, P1);
        }
        float kl = KL[c];
        float xv0 = x[c*VOX + v];
        float xv1 = x[c*VOX + v + 256];
        outAll[c*VOX + v]       = fmaxf(0.f, fmaf(xv0, P0, kl));
        outAll[c*VOX + v + 256] = fmaxf(0.f, fmaf(xv1, P1, kl));
    }
}

extern "C" void kernel_launch(void* const* d_in, const int* in_sizes, int n_in,
                              void* d_out, int out_size, void* d_ws, size_t ws_size,
                              hipStream_t stream)
{
    const float* x     = (const float*)d_in[0];
    const float* clsw  = (const float*)d_in[1];
    const float* clsb  = (const float*)d_in[2];
    const float* cfr   = (const float*)d_in[3];
    const float* gamma = (const float*)d_in[4];
    const float* beta  = (const float*)d_in[5];

    float* out   = (float*)d_out;
    float* logit = out + (size_t)CCH*VOX;     // second output
    float* masks = out;                       // scratch: out[0 .. 20V)
    float* G     = out + (size_t)NCL*VOX;     // scratch: out[20V .. 40V)

    float* ws    = (float*)d_ws;
    float* mxp   = ws;                        // V
    float* Mxp   = ws + VOX;                  // V
    unsigned* keys = (unsigned*)(ws + 2*(size_t)VOX);   // 40
    float* hminA = ws + 2*(size_t)VOX + 64;   // 20
    float* invR  = hminA + NCL;               // 20
    float* part  = ws + 2*(size_t)VOX + 128;  // 512*2560
    float* aArr  = part + 512*(NCL*CCH*2);    // 1280
    float* kcArr = aArr + NCL*CCH;            // 1280
    float* KcA   = kcArr + NCL*CCH;           // 64
    float* zpg   = KcA + CCH;                 // 256 (zero page for OOB lanes)

    k_init<<<1, 64, 0, stream>>>(keys, zpg);
    k_logit_softmax<<<VOX/1024, 256, 0, stream>>>(x, clsw, clsb, masks, logit, mxp, Mxp);
    k_conv13<<<dim3(4, 16, NCL), 256, 0, stream>>>(masks, mxp, Mxp, cfr, G, keys, zpg);
    k_thr<<<1, 32, 0, stream>>>(keys, hminA, invR);
    k_region<<<dim3(VOX/256, NCL), 256, 0, stream>>>(G, mxp, hminA, invR);
    k_stats<<<512, 256, 0, stream>>>(x, G, part);
    k_params<<<NCL, CCH, 0, stream>>>(part, gamma, beta, aArr, kcArr);
    k_kcol<<<1, CCH, 0, stream>>>(kcArr, KcA);
    k_final<<<VOX/512, 256, 0, stream>>>(x, out, aArr, KcA);
}